// Round 1
// baseline (228.464 us; speedup 1.0000x reference)
//
#include <hip/hip_runtime.h>
#include <hip/hip_bf16.h>
#include <math.h>

// Problem constants (fixed by the reference)
#define BB 2
#define HH 64
#define WW 64
#define DM 192            // d_model
#define DI 384            // d_inner
#define NS 16             // d_state
#define RK 12             // dt_rank
#define LL (HH*WW)        // 4096
#define ML (BB*LL)        // 8192 rows
#define NC 128            // scan chunks
#define CL 32             // chunk length; NC*CL == LL

// ---------------------------------------------------------------------------
// GEMM: C[m,n] = sum_k A[m,k] * Bw[n,k]   (A: MxK row-major, Bw: NxK row-major)
// 64x64 block tile, 256 threads, 4x4 per thread, TK=16.
// ---------------------------------------------------------------------------
__global__ __launch_bounds__(256) void gemm_nt(const float* __restrict__ A,
                                               const float* __restrict__ Bw,
                                               float* __restrict__ C,
                                               int M, int N, int K) {
  __shared__ float As[16][64];
  __shared__ float Bs[16][64];
  const int bm = blockIdx.y * 64;
  const int bn = blockIdx.x * 64;
  const int tid = threadIdx.x;
  const int tm = (tid & 15) * 4;
  const int tn = (tid >> 4) * 4;
  const int lr = tid >> 2;         // 0..63 (row within tile for loads)
  const int lk = (tid & 3) * 4;    // 0,4,8,12 (k within TK for loads)
  float acc[4][4] = {};
  for (int k0 = 0; k0 < K; k0 += 16) {
    const float4 va = *reinterpret_cast<const float4*>(&A [(size_t)(bm + lr) * K + k0 + lk]);
    const float4 vb = *reinterpret_cast<const float4*>(&Bw[(size_t)(bn + lr) * K + k0 + lk]);
    As[lk+0][lr] = va.x; As[lk+1][lr] = va.y; As[lk+2][lr] = va.z; As[lk+3][lr] = va.w;
    Bs[lk+0][lr] = vb.x; Bs[lk+1][lr] = vb.y; Bs[lk+2][lr] = vb.z; Bs[lk+3][lr] = vb.w;
    __syncthreads();
    #pragma unroll
    for (int kk = 0; kk < 16; ++kk) {
      float a[4], b[4];
      #pragma unroll
      for (int i = 0; i < 4; ++i) { a[i] = As[kk][tm+i]; b[i] = Bs[kk][tn+i]; }
      #pragma unroll
      for (int i = 0; i < 4; ++i)
        #pragma unroll
        for (int j = 0; j < 4; ++j)
          acc[i][j] = fmaf(a[i], b[j], acc[i][j]);
    }
    __syncthreads();
  }
  #pragma unroll
  for (int i = 0; i < 4; ++i) {
    float4 v = make_float4(acc[i][0], acc[i][1], acc[i][2], acc[i][3]);
    *reinterpret_cast<float4*>(&C[(size_t)(bm + tm + i) * N + bn + tn]) = v;
  }
}

// ---------------------------------------------------------------------------
// Depthwise 3x3 conv (SAME, zero pad) + bias + SiLU.
// xz: (ML, 768), channel d in [0,384). Writes x_seq: (ML, 384).
// ---------------------------------------------------------------------------
__global__ __launch_bounds__(256) void conv_silu(const float* __restrict__ xz,
                                                 const float* __restrict__ conv_w,
                                                 const float* __restrict__ conv_b,
                                                 float* __restrict__ x_seq) {
  int idx = blockIdx.x * 256 + threadIdx.x;   // over ML*DI
  int d = idx % DI;
  int l = (idx / DI) % LL;
  int b = idx / (DI * LL);
  int h = l >> 6, w = l & 63;
  float acc = conv_b[d];
  #pragma unroll
  for (int kh = 0; kh < 3; ++kh) {
    int hh = h + kh - 1;
    if (hh < 0 || hh >= HH) continue;
    #pragma unroll
    for (int kw = 0; kw < 3; ++kw) {
      int ww2 = w + kw - 1;
      if (ww2 < 0 || ww2 >= WW) continue;
      acc = fmaf(xz[((size_t)(b * LL + hh * WW + ww2)) * 768 + d],
                 conv_w[d * 9 + kh * 3 + kw], acc);
    }
  }
  float sv = acc / (1.f + __expf(-acc));      // silu
  x_seq[idx] = sv;
}

// ---------------------------------------------------------------------------
// Per-(b,l): x_dbl = x_proj_w @ x_seq;  delta = softplus(dt_proj(x_dbl[:12]) + 2*dt_bias)
// Bv = x_dbl[12:28];  Cv = x_dbl[28:44] + prompt_proj_w @ prompt.
// Block handles 16 rows.
// ---------------------------------------------------------------------------
__global__ __launch_bounds__(256) void proj_kernel(const float* __restrict__ x_seq,
                                                   const float* __restrict__ prompt,
                                                   const float* __restrict__ x_proj_w,
                                                   const float* __restrict__ dt_proj_w,
                                                   const float* __restrict__ dt_proj_b,
                                                   const float* __restrict__ prompt_proj_w,
                                                   float* __restrict__ delta,
                                                   float* __restrict__ Bv,
                                                   float* __restrict__ Cv) {
  __shared__ float xs[16][385];   // pad -> bank stride 1
  __shared__ float pr[16][193];
  __shared__ float xd[16][48];
  __shared__ float sdt[384][13];  // dt_proj_w staged, pad 13 (coprime 32)
  const int tid = threadIdx.x;
  const size_t l0 = (size_t)blockIdx.x * 16;

  for (int idx = tid; idx < 16 * 96; idx += 256) {
    int r = idx / 96, cq = (idx % 96) * 4;
    const float4 v = *reinterpret_cast<const float4*>(&x_seq[(l0 + r) * DI + cq]);
    xs[r][cq] = v.x; xs[r][cq+1] = v.y; xs[r][cq+2] = v.z; xs[r][cq+3] = v.w;
  }
  for (int idx = tid; idx < 16 * 48; idx += 256) {
    int r = idx / 48, cq = (idx % 48) * 4;
    const float4 v = *reinterpret_cast<const float4*>(&prompt[(l0 + r) * DM + cq]);
    pr[r][cq] = v.x; pr[r][cq+1] = v.y; pr[r][cq+2] = v.z; pr[r][cq+3] = v.w;
  }
  for (int idx = tid; idx < DI * RK; idx += 256)
    sdt[idx / RK][idx % RK] = dt_proj_w[idx];
  __syncthreads();

  // x_dbl: lanes r-fast so w rows broadcast within the wave
  for (int o = tid; o < 16 * 44; o += 256) {
    int r = o & 15, j = o >> 4;
    const float* wrow = &x_proj_w[j * DI];
    float acc = 0.f;
    for (int c = 0; c < DI; ++c) acc = fmaf(xs[r][c], wrow[c], acc);
    xd[r][j] = acc;
  }
  __syncthreads();

  // delta (coalesced writes; dt_proj_w from LDS)
  for (int o = tid; o < 16 * DI; o += 256) {
    int r = o / DI, d = o % DI;
    float acc = 2.0f * dt_proj_b[d];          // bias applied twice (faithful to ref)
    #pragma unroll
    for (int j = 0; j < RK; ++j) acc = fmaf(xd[r][j], sdt[d][j], acc);
    float sp = fmaxf(acc, 0.f) + log1pf(__expf(-fabsf(acc)));   // softplus
    delta[(l0 + r) * DI + d] = sp;
  }

  // B and C (exactly 256 outputs)
  {
    int o = tid;
    int r = o & 15, n = o >> 4;
    Bv[(l0 + r) * NS + n] = xd[r][12 + n];
    float acc = xd[r][28 + n];
    const float* prow = &prompt_proj_w[n * DM];
    for (int c = 0; c < DM; ++c) acc = fmaf(pr[r][c], prow[c], acc);
    Cv[(l0 + r) * NS + n] = acc;
  }
}

// ---------------------------------------------------------------------------
// Chunked scan pass 1: per (b, chunk, d) compute P_n = prod(dA), Q_n = local h.
// ---------------------------------------------------------------------------
__global__ __launch_bounds__(DI) void scan_pass1(const float* __restrict__ delta,
                                                 const float* __restrict__ x_seq,
                                                 const float* __restrict__ Bv,
                                                 const float* __restrict__ A_log,
                                                 float* __restrict__ Pb,
                                                 float* __restrict__ Qb) {
  const int d = threadIdx.x;
  const int c = blockIdx.x % NC;
  const int b = blockIdx.x / NC;
  __shared__ float sB[CL][NS];
  for (int idx = threadIdx.x; idx < CL * NS; idx += DI)
    sB[idx / NS][idx % NS] = Bv[(size_t)(b * LL + c * CL) * NS + idx];

  float a2[NS], h[NS], p[NS];
  #pragma unroll
  for (int n = 0; n < NS; ++n) {
    a2[n] = -__expf(A_log[d * NS + n]) * 1.4426950408889634f;  // A * log2(e)
    h[n] = 0.f; p[n] = 1.f;
  }
  __syncthreads();

  const size_t rowbase = (size_t)(b * LL + c * CL) * DI + d;
  for (int s = 0; s < CL; ++s) {
    float de = delta[rowbase + (size_t)s * DI];
    float du = de * x_seq[rowbase + (size_t)s * DI];
    #pragma unroll
    for (int n = 0; n < NS; ++n) {
      float e = exp2f(de * a2[n]);
      h[n] = fmaf(e, h[n], du * sB[s][n]);
      p[n] *= e;
    }
  }
  const size_t base = ((size_t)(b * NC + c) * DI + d) * NS;
  #pragma unroll
  for (int n = 0; n < NS; n += 4) {
    *reinterpret_cast<float4*>(&Pb[base + n]) = make_float4(p[n], p[n+1], p[n+2], p[n+3]);
    *reinterpret_cast<float4*>(&Qb[base + n]) = make_float4(h[n], h[n+1], h[n+2], h[n+3]);
  }
}

// ---------------------------------------------------------------------------
// Combine chunk states: per (b,d,n) scan over NC chunks sequentially.
// ---------------------------------------------------------------------------
__global__ __launch_bounds__(256) void scan_combine(const float* __restrict__ Pb,
                                                    const float* __restrict__ Qb,
                                                    float* __restrict__ hinit) {
  const int t = blockIdx.x * 256 + threadIdx.x;  // 12288 total
  const int b = t / (DI * NS);
  const int dn = t % (DI * NS);
  float h = 0.f;
  size_t idx = (size_t)(b * NC) * DI * NS + dn;
  float P = Pb[idx], Q = Qb[idx];
  for (int c = 0; c < NC; ++c) {
    size_t nxt = idx + DI * NS;
    float P2 = 0.f, Q2 = 0.f;
    if (c + 1 < NC) { P2 = Pb[nxt]; Q2 = Qb[nxt]; }   // prefetch off the chain
    hinit[idx] = h;
    h = fmaf(P, h, Q);
    P = P2; Q = Q2; idx = nxt;
  }
}

// ---------------------------------------------------------------------------
// Chunked scan pass 2: replay chunk from true initial state, emit y = h·C + Dp*u.
// ---------------------------------------------------------------------------
__global__ __launch_bounds__(DI) void scan_pass2(const float* __restrict__ delta,
                                                 const float* __restrict__ x_seq,
                                                 const float* __restrict__ Bv,
                                                 const float* __restrict__ Cv,
                                                 const float* __restrict__ A_log,
                                                 const float* __restrict__ Dp,
                                                 const float* __restrict__ hinit,
                                                 float* __restrict__ y) {
  const int d = threadIdx.x;
  const int c = blockIdx.x % NC;
  const int b = blockIdx.x / NC;
  __shared__ float sB[CL][NS];
  __shared__ float sC[CL][NS];
  for (int idx = threadIdx.x; idx < CL * NS; idx += DI) {
    size_t g = (size_t)(b * LL + c * CL) * NS + idx;
    sB[idx / NS][idx % NS] = Bv[g];
    sC[idx / NS][idx % NS] = Cv[g];
  }
  float a2[NS], h[NS];
  const size_t hbase = ((size_t)(b * NC + c) * DI + d) * NS;
  #pragma unroll
  for (int n = 0; n < NS; n += 4) {
    float4 hv = *reinterpret_cast<const float4*>(&hinit[hbase + n]);
    h[n] = hv.x; h[n+1] = hv.y; h[n+2] = hv.z; h[n+3] = hv.w;
  }
  #pragma unroll
  for (int n = 0; n < NS; ++n)
    a2[n] = -__expf(A_log[d * NS + n]) * 1.4426950408889634f;
  const float Dd = Dp[d];
  __syncthreads();

  const size_t rowbase = (size_t)(b * LL + c * CL) * DI + d;
  for (int s = 0; s < CL; ++s) {
    float de = delta[rowbase + (size_t)s * DI];
    float u  = x_seq[rowbase + (size_t)s * DI];
    float du = de * u;
    float acc = Dd * u;
    #pragma unroll
    for (int n = 0; n < NS; ++n) {
      float e = exp2f(de * a2[n]);
      h[n] = fmaf(e, h[n], du * sB[s][n]);
      acc = fmaf(h[n], sC[s][n], acc);
    }
    y[rowbase + (size_t)s * DI] = acc;
  }
}

// ---------------------------------------------------------------------------
// LayerNorm over d=384 + SiLU(z) gate. 8 rows per block, 32 lanes per row.
// ---------------------------------------------------------------------------
__global__ __launch_bounds__(256) void ln_gate(const float* __restrict__ y,
                                               const float* __restrict__ xz,
                                               const float* __restrict__ ln_g,
                                               const float* __restrict__ ln_b,
                                               float* __restrict__ yg) {
  const int tid = threadIdx.x;
  const int r = tid >> 5, lane = tid & 31;
  const size_t row = (size_t)blockIdx.x * 8 + r;
  const float* yr = &y[row * DI];
  float v[12];
  float sum = 0.f, sq = 0.f;
  #pragma unroll
  for (int k = 0; k < 12; ++k) {
    v[k] = yr[lane + k * 32];
    sum += v[k];
    sq = fmaf(v[k], v[k], sq);
  }
  #pragma unroll
  for (int off = 16; off >= 1; off >>= 1) {
    sum += __shfl_xor(sum, off, 32);
    sq  += __shfl_xor(sq,  off, 32);
  }
  const float mu = sum * (1.f / DI);
  const float var = sq * (1.f / DI) - mu * mu;
  const float rstd = rsqrtf(var + 1e-5f);
  const float* zr = &xz[row * 768 + DI];
  float* og = &yg[row * DI];
  #pragma unroll
  for (int k = 0; k < 12; ++k) {
    int dd = lane + k * 32;
    float t = (v[k] - mu) * rstd * ln_g[dd] + ln_b[dd];
    float z = zr[dd];
    og[dd] = t * (z / (1.f + __expf(-z)));
  }
}

// ---------------------------------------------------------------------------
extern "C" void kernel_launch(void* const* d_in, const int* in_sizes, int n_in,
                              void* d_out, int out_size, void* d_ws, size_t ws_size,
                              hipStream_t stream) {
  const float* x             = (const float*)d_in[0];
  const float* prompt        = (const float*)d_in[1];
  const float* in_proj_w     = (const float*)d_in[2];
  const float* conv_w        = (const float*)d_in[3];
  const float* conv_b        = (const float*)d_in[4];
  const float* x_proj_w      = (const float*)d_in[5];
  const float* dt_proj_w     = (const float*)d_in[6];
  const float* dt_proj_b     = (const float*)d_in[7];
  const float* A_log         = (const float*)d_in[8];
  const float* Dp            = (const float*)d_in[9];
  const float* prompt_proj_w = (const float*)d_in[10];
  const float* ln_g          = (const float*)d_in[11];
  const float* ln_b          = (const float*)d_in[12];
  const float* out_proj_w    = (const float*)d_in[13];
  float* out = (float*)d_out;
  float* ws = (float*)d_ws;

  // workspace layout (floats); peak ~79 MB
  float* xz    = ws;                               // ML*768
  float* xseq  = xz    + (size_t)ML * 768;         // ML*DI
  float* delta = xseq  + (size_t)ML * DI;          // ML*DI
  float* bv    = delta + (size_t)ML * DI;          // ML*NS
  float* cv    = bv    + (size_t)ML * NS;          // ML*NS
  float* pb    = cv    + (size_t)ML * NS;          // BB*NC*DI*NS
  float* qb    = pb    + (size_t)BB * NC * DI * NS;
  float* hin   = qb    + (size_t)BB * NC * DI * NS;
  float* ybuf  = hin   + (size_t)BB * NC * DI * NS; // ML*DI
  float* yg    = delta;                             // delta is dead after pass2

  gemm_nt<<<dim3(768 / 64, ML / 64), 256, 0, stream>>>(x, in_proj_w, xz, ML, 768, DM);
  conv_silu<<<(ML * DI) / 256, 256, 0, stream>>>(xz, conv_w, conv_b, xseq);
  proj_kernel<<<ML / 16, 256, 0, stream>>>(xseq, prompt, x_proj_w, dt_proj_w,
                                           dt_proj_b, prompt_proj_w, delta, bv, cv);
  scan_pass1<<<BB * NC, DI, 0, stream>>>(delta, xseq, bv, A_log, pb, qb);
  scan_combine<<<(BB * DI * NS) / 256, 256, 0, stream>>>(pb, qb, hin);
  scan_pass2<<<BB * NC, DI, 0, stream>>>(delta, xseq, bv, cv, A_log, Dp, hin, ybuf);
  ln_gate<<<ML / 8, 256, 0, stream>>>(ybuf, xz, ln_g, ln_b, yg);
  gemm_nt<<<dim3(DM / 64, ML / 64), 256, 0, stream>>>(yg, out_proj_w, out, ML, DM, DI);
}

// Round 2
// 223.019 us; speedup vs baseline: 1.0244x; 1.0244x over previous
//
#include <hip/hip_runtime.h>
#include <hip/hip_bf16.h>
#include <math.h>

// Problem constants (fixed by the reference)
#define BB 2
#define HH 64
#define WW 64
#define DM 192            // d_model
#define DI 384            // d_inner
#define NS 16             // d_state
#define RK 12             // dt_rank
#define LL (HH*WW)        // 4096
#define ML (BB*LL)        // 8192 rows
#define NC 256            // scan chunks
#define CL 16             // chunk length; NC*CL == LL

typedef __attribute__((ext_vector_type(8))) short short8v;   // 8 bf16 (4 VGPRs)
typedef __attribute__((ext_vector_type(4))) float f32x4;

__device__ __forceinline__ ushort f2bf(float f) {
  unsigned u = __float_as_uint(f);
  u += 0x7fffu + ((u >> 16) & 1u);          // RNE
  return (ushort)(u >> 16);
}
__device__ __forceinline__ float bf2f(ushort h) {
  return __uint_as_float(((unsigned)h) << 16);
}
__device__ __forceinline__ void split2(float f, ushort& h, ushort& l) {
  h = f2bf(f);
  l = f2bf(f - bf2f(h));                    // residual; h+l ~ f to 2^-17 rel
}

// ---------------------------------------------------------------------------
// Weight conversion: split f32 -> (bf16 hi, bf16 lo). Three weights packed in
// one launch; x_proj_w is zero-padded from 44 to 64 rows.
// ---------------------------------------------------------------------------
__global__ __launch_bounds__(256) void convert_w(
    const float* __restrict__ w1, const float* __restrict__ w2, const float* __restrict__ wx,
    ushort* __restrict__ w1h, ushort* __restrict__ w1l,
    ushort* __restrict__ w2h, ushort* __restrict__ w2l,
    ushort* __restrict__ wxh, ushort* __restrict__ wxl) {
  const int N1 = 768 * DM;        // in_proj_w
  const int N2 = DM * DI;         // out_proj_w
  const int N3 = 64 * DI;         // x_proj_w padded
  int i = blockIdx.x * 256 + threadIdx.x;
  ushort h, l;
  if (i < N1) {
    split2(w1[i], h, l); w1h[i] = h; w1l[i] = l;
  } else if (i < N1 + N2) {
    int j = i - N1;
    split2(w2[j], h, l); w2h[j] = h; w2l[j] = l;
  } else if (i < N1 + N2 + N3) {
    int j = i - N1 - N2;
    float v = (j < 44 * DI) ? wx[j] : 0.f;
    split2(v, h, l); wxh[j] = h; wxl[j] = l;
  }
}

// ---------------------------------------------------------------------------
// Split-bf16 MFMA GEMM:  C[m,n] = sum_k A[m,k] * W[n,k]
// A: f32 MxK row-major (split to hi/lo on the fly during staging)
// W: pre-split bf16 (Wh, Wl), NxK row-major
// C = Ah*Wh + Ah*Wl + Al*Wh  (Al*Wl dropped, ~2^-16 relative)
// Block tile 128 x BN, 4 waves (2x2), wave tile 64 x BN/2, K-step 32.
// mfma_f32_16x16x32_bf16: A-frag row=lane&15, k=(lane>>4)*8+j;
// B-frag col=lane&15, k=(lane>>4)*8+j; D row=(lane>>4)*4+r, col=lane&15.
// ---------------------------------------------------------------------------
template<int BN>
__global__ __launch_bounds__(256) void gemm_bf16s(
    const float* __restrict__ A,
    const ushort* __restrict__ Wh, const ushort* __restrict__ Wl,
    float* __restrict__ C, int M, int N, int K) {
  constexpr int RS = 40;                 // LDS row stride (bf16) = 32 + 8 pad
  constexpr int NR = BN / 32;            // n-fragments per wave (4 or 2)
  __shared__ __align__(16) ushort sAh[128 * RS];
  __shared__ __align__(16) ushort sAl[128 * RS];
  __shared__ __align__(16) ushort sBh[BN * RS];
  __shared__ __align__(16) ushort sBl[BN * RS];
  const int tid = threadIdx.x;
  const int lane = tid & 63, wid = tid >> 6;
  const int wm = (wid >> 1) * 64;
  const int wn = (wid & 1) * (BN / 2);
  const int bm = blockIdx.y * 128;
  const int bn = blockIdx.x * BN;
  const int r16 = lane & 15;
  const int kb8 = (lane >> 4) * 8;

  f32x4 acc[4][NR];
  #pragma unroll
  for (int m = 0; m < 4; ++m)
    #pragma unroll
    for (int n = 0; n < NR; ++n)
      acc[m][n] = (f32x4){0.f, 0.f, 0.f, 0.f};

  for (int k0 = 0; k0 < K; k0 += 32) {
    __syncthreads();   // WAR: previous iteration's fragment reads complete
    // stage A-tile (128x32 f32), splitting to hi/lo bf16
    for (int i = tid; i < 128 * 8; i += 256) {
      int row = i >> 3, c4 = (i & 7) << 2;
      float4 v = *reinterpret_cast<const float4*>(&A[(size_t)(bm + row) * K + k0 + c4]);
      ushort4 h, l;
      split2(v.x, h.x, l.x); split2(v.y, h.y, l.y);
      split2(v.z, h.z, l.z); split2(v.w, h.w, l.w);
      *reinterpret_cast<ushort4*>(&sAh[row * RS + c4]) = h;
      *reinterpret_cast<ushort4*>(&sAl[row * RS + c4]) = l;
    }
    // stage W-tile (BNx32 bf16 hi/lo)
    for (int i = tid; i < BN * 4; i += 256) {
      int row = i >> 2, kc = (i & 3) << 3;
      *reinterpret_cast<short8v*>(&sBh[row * RS + kc]) =
          *reinterpret_cast<const short8v*>(&Wh[(size_t)(bn + row) * K + k0 + kc]);
      *reinterpret_cast<short8v*>(&sBl[row * RS + kc]) =
          *reinterpret_cast<const short8v*>(&Wl[(size_t)(bn + row) * K + k0 + kc]);
    }
    __syncthreads();

    short8v ah[4], al[4], bh[NR], bl[NR];
    #pragma unroll
    for (int m = 0; m < 4; ++m) {
      int off = (wm + m * 16 + r16) * RS + kb8;
      ah[m] = *reinterpret_cast<const short8v*>(&sAh[off]);
      al[m] = *reinterpret_cast<const short8v*>(&sAl[off]);
    }
    #pragma unroll
    for (int n = 0; n < NR; ++n) {
      int off = (wn + n * 16 + r16) * RS + kb8;
      bh[n] = *reinterpret_cast<const short8v*>(&sBh[off]);
      bl[n] = *reinterpret_cast<const short8v*>(&sBl[off]);
    }
    #pragma unroll
    for (int m = 0; m < 4; ++m)
      #pragma unroll
      for (int n = 0; n < NR; ++n)
        acc[m][n] = __builtin_amdgcn_mfma_f32_16x16x32_bf16(ah[m], bh[n], acc[m][n], 0, 0, 0);
    #pragma unroll
    for (int m = 0; m < 4; ++m)
      #pragma unroll
      for (int n = 0; n < NR; ++n)
        acc[m][n] = __builtin_amdgcn_mfma_f32_16x16x32_bf16(ah[m], bl[n], acc[m][n], 0, 0, 0);
    #pragma unroll
    for (int m = 0; m < 4; ++m)
      #pragma unroll
      for (int n = 0; n < NR; ++n)
        acc[m][n] = __builtin_amdgcn_mfma_f32_16x16x32_bf16(al[m], bh[n], acc[m][n], 0, 0, 0);
  }

  const int cr = (lane >> 4) * 4;
  #pragma unroll
  for (int m = 0; m < 4; ++m)
    #pragma unroll
    for (int n = 0; n < NR; ++n) {
      int row = bm + wm + m * 16 + cr;
      int col = bn + wn + n * 16 + r16;
      #pragma unroll
      for (int r = 0; r < 4; ++r)
        C[(size_t)(row + r) * N + col] = acc[m][n][r];
    }
}

// ---------------------------------------------------------------------------
// Depthwise 3x3 conv (SAME, zero pad) + bias + SiLU. xz: (ML,768), d in [0,384).
// ---------------------------------------------------------------------------
__global__ __launch_bounds__(256) void conv_silu(const float* __restrict__ xz,
                                                 const float* __restrict__ conv_w,
                                                 const float* __restrict__ conv_b,
                                                 float* __restrict__ x_seq) {
  int idx = blockIdx.x * 256 + threadIdx.x;   // over ML*DI
  int d = idx % DI;
  int l = (idx / DI) % LL;
  int b = idx / (DI * LL);
  int h = l >> 6, w = l & 63;
  float acc = conv_b[d];
  #pragma unroll
  for (int kh = 0; kh < 3; ++kh) {
    int hh = h + kh - 1;
    if (hh < 0 || hh >= HH) continue;
    #pragma unroll
    for (int kw = 0; kw < 3; ++kw) {
      int ww2 = w + kw - 1;
      if (ww2 < 0 || ww2 >= WW) continue;
      acc = fmaf(xz[((size_t)(b * LL + hh * WW + ww2)) * 768 + d],
                 conv_w[d * 9 + kh * 3 + kw], acc);
    }
  }
  x_seq[idx] = acc / (1.f + __expf(-acc));    // silu
}

// ---------------------------------------------------------------------------
// finish: per (b,l): delta = softplus(xdbl[:12] @ dt_w^T + 2*dt_b) (faithful
// double-bias), B = xdbl[12:28], C = xdbl[28:44] + prompt @ pw^T.
// 16 rows per block; everything served from LDS.
// ---------------------------------------------------------------------------
__global__ __launch_bounds__(256) void finish_kernel(
    const float* __restrict__ xdbl,          // ML x 64
    const float* __restrict__ prompt,        // ML x 192
    const float* __restrict__ dt_proj_w,     // 384 x 12
    const float* __restrict__ dt_proj_b,     // 384
    const float* __restrict__ prompt_proj_w, // 16 x 192
    float* __restrict__ delta, float* __restrict__ Bv, float* __restrict__ Cv) {
  __shared__ float xd[16][64];
  __shared__ float pr[16][193];
  __shared__ float pw[16][193];
  __shared__ float sdt[12][384];
  __shared__ float sdb[384];
  const int tid = threadIdx.x;
  const size_t l0 = (size_t)blockIdx.x * 16;

  {  // xd: 16x64 = 256 float4, one per thread
    int r = tid >> 4, c4 = (tid & 15) << 2;
    float4 v = *reinterpret_cast<const float4*>(&xdbl[(l0 + r) * 64 + c4]);
    xd[r][c4] = v.x; xd[r][c4+1] = v.y; xd[r][c4+2] = v.z; xd[r][c4+3] = v.w;
  }
  for (int i = tid; i < 768; i += 256) {   // prompt rows 16x192
    int r = i / 48, c4 = (i % 48) << 2;
    float4 v = *reinterpret_cast<const float4*>(&prompt[(l0 + r) * DM + c4]);
    pr[r][c4] = v.x; pr[r][c4+1] = v.y; pr[r][c4+2] = v.z; pr[r][c4+3] = v.w;
  }
  for (int i = tid; i < 768; i += 256) {   // prompt_proj_w 16x192
    int r = i / 48, c4 = (i % 48) << 2;
    float4 v = *reinterpret_cast<const float4*>(&prompt_proj_w[r * DM + c4]);
    pw[r][c4] = v.x; pw[r][c4+1] = v.y; pw[r][c4+2] = v.z; pw[r][c4+3] = v.w;
  }
  for (int i = tid; i < DI * RK; i += 256)  // dt_proj_w transposed
    sdt[i % RK][i / RK] = dt_proj_w[i];
  for (int i = tid; i < DI; i += 256)
    sdb[i] = 2.0f * dt_proj_b[i];           // bias applied twice (faithful)
  __syncthreads();

  // delta
  for (int o = tid; o < 16 * DI; o += 256) {
    int r = o / DI, dd = o % DI;
    float acc = sdb[dd];
    #pragma unroll
    for (int j = 0; j < RK; ++j) acc = fmaf(xd[r][j], sdt[j][dd], acc);
    float sp = fmaxf(acc, 0.f) + log1pf(__expf(-fabsf(acc)));  // softplus
    delta[(l0 + r) * DI + dd] = sp;
  }
  // B and C (exactly 256 outputs; lanes n-fast for coalesced writes)
  {
    int r = tid >> 4, n = tid & 15;
    Bv[(l0 + r) * NS + n] = xd[r][12 + n];
    float acc = xd[r][28 + n];
    for (int c = 0; c < DM; ++c) acc = fmaf(pr[r][c], pw[n][c], acc);
    Cv[(l0 + r) * NS + n] = acc;
  }
}

// ---------------------------------------------------------------------------
// Chunked scan pass 1: per (b, chunk, d) compute P_n = prod(dA), Q_n = local h.
// ---------------------------------------------------------------------------
__global__ __launch_bounds__(DI) void scan_pass1(const float* __restrict__ delta,
                                                 const float* __restrict__ x_seq,
                                                 const float* __restrict__ Bv,
                                                 const float* __restrict__ A_log,
                                                 float* __restrict__ Pb,
                                                 float* __restrict__ Qb) {
  const int d = threadIdx.x;
  const int c = blockIdx.x & (NC - 1);
  const int b = blockIdx.x >> 8;            // NC == 256
  __shared__ float sB[CL][NS];
  for (int idx = threadIdx.x; idx < CL * NS; idx += DI)
    sB[idx >> 4][idx & 15] = Bv[(size_t)(b * LL + c * CL) * NS + idx];

  float a2[NS], h[NS], p[NS];
  #pragma unroll
  for (int n = 0; n < NS; ++n) {
    a2[n] = -__expf(A_log[d * NS + n]) * 1.4426950408889634f;  // A * log2(e)
    h[n] = 0.f; p[n] = 1.f;
  }
  __syncthreads();

  const size_t rowbase = (size_t)(b * LL + c * CL) * DI + d;
  for (int s = 0; s < CL; ++s) {
    float de = delta[rowbase + (size_t)s * DI];
    float du = de * x_seq[rowbase + (size_t)s * DI];
    #pragma unroll
    for (int n = 0; n < NS; ++n) {
      float e = exp2f(de * a2[n]);
      h[n] = fmaf(e, h[n], du * sB[s][n]);
      p[n] *= e;
    }
  }
  const size_t base = ((size_t)(b * NC + c) * DI + d) * NS;
  #pragma unroll
  for (int n = 0; n < NS; n += 4) {
    *reinterpret_cast<float4*>(&Pb[base + n]) = make_float4(p[n], p[n+1], p[n+2], p[n+3]);
    *reinterpret_cast<float4*>(&Qb[base + n]) = make_float4(h[n], h[n+1], h[n+2], h[n+3]);
  }
}

// ---------------------------------------------------------------------------
// Combine chunk states: per (b,d,n) scan over NC chunks, 8-deep prefetch.
// NOTE: Hout may alias Pb (in-place) -- params intentionally NOT __restrict__.
// ---------------------------------------------------------------------------
__global__ __launch_bounds__(256) void scan_combine(const float* Pb, const float* Qb,
                                                    float* Hout) {
  const int t = blockIdx.x * 256 + threadIdx.x;   // 12288 total
  const int b = t / (DI * NS);
  const int dn = t % (DI * NS);
  const size_t S = DI * NS;
  const size_t base = (size_t)b * NC * S + dn;
  float h = 0.f;
  float P[8], Q[8];
  #pragma unroll
  for (int j = 0; j < 8; ++j) { P[j] = Pb[base + (size_t)j * S]; Q[j] = Qb[base + (size_t)j * S]; }
  for (int c0 = 0; c0 < NC; c0 += 8) {
    float P2[8] = {0,0,0,0,0,0,0,0}, Q2[8] = {0,0,0,0,0,0,0,0};
    if (c0 + 8 < NC) {
      #pragma unroll
      for (int j = 0; j < 8; ++j) {
        P2[j] = Pb[base + (size_t)(c0 + 8 + j) * S];
        Q2[j] = Qb[base + (size_t)(c0 + 8 + j) * S];
      }
    }
    #pragma unroll
    for (int j = 0; j < 8; ++j) {
      Hout[base + (size_t)(c0 + j) * S] = h;
      h = fmaf(P[j], h, Q[j]);
    }
    #pragma unroll
    for (int j = 0; j < 8; ++j) { P[j] = P2[j]; Q[j] = Q2[j]; }
  }
}

// ---------------------------------------------------------------------------
// Pass 2 + fused LayerNorm + SiLU gate. Block = 384 threads (one per d),
// CL=16 rows per block. Block-wide LN reduce per step (6 waves).
// ---------------------------------------------------------------------------
__global__ __launch_bounds__(DI) void scan_pass2_ln(
    const float* __restrict__ delta, const float* __restrict__ x_seq,
    const float* __restrict__ Bv, const float* __restrict__ Cv,
    const float* __restrict__ A_log, const float* __restrict__ Dp,
    const float* __restrict__ hin, const float* __restrict__ xz,
    const float* __restrict__ ln_g, const float* __restrict__ ln_b,
    float* __restrict__ yg) {
  const int d = threadIdx.x;
  const int c = blockIdx.x & (NC - 1);
  const int b = blockIdx.x >> 8;
  __shared__ float sB[CL][NS], sC[CL][NS];
  __shared__ float red[2][2][6];
  for (int idx = threadIdx.x; idx < CL * NS; idx += DI) {
    size_t g = (size_t)(b * LL + c * CL) * NS + idx;
    sB[idx >> 4][idx & 15] = Bv[g];
    sC[idx >> 4][idx & 15] = Cv[g];
  }
  float a2[NS], h[NS];
  const size_t hbase = ((size_t)(b * NC + c) * DI + d) * NS;
  #pragma unroll
  for (int n = 0; n < NS; n += 4) {
    float4 hv = *reinterpret_cast<const float4*>(&hin[hbase + n]);
    h[n] = hv.x; h[n+1] = hv.y; h[n+2] = hv.z; h[n+3] = hv.w;
  }
  #pragma unroll
  for (int n = 0; n < NS; ++n)
    a2[n] = -__expf(A_log[d * NS + n]) * 1.4426950408889634f;
  const float Dd = Dp[d];
  const float gg = ln_g[d], bb2 = ln_b[d];
  const int wv = d >> 6, ln0 = d & 63;
  __syncthreads();

  const size_t row0 = (size_t)(b * LL + c * CL);
  for (int s = 0; s < CL; ++s) {
    const size_t row = row0 + s;
    float de = delta[row * DI + d];
    float u  = x_seq[row * DI + d];
    float du = de * u;
    float acc = Dd * u;
    #pragma unroll
    for (int n = 0; n < NS; ++n) {
      float e = exp2f(de * a2[n]);
      h[n] = fmaf(e, h[n], du * sB[s][n]);
      acc = fmaf(h[n], sC[s][n], acc);
    }
    // block LayerNorm over 384 threads
    float sum = acc, sq = acc * acc;
    #pragma unroll
    for (int off = 32; off >= 1; off >>= 1) {
      sum += __shfl_xor(sum, off, 64);
      sq  += __shfl_xor(sq,  off, 64);
    }
    if (ln0 == 0) { red[s & 1][0][wv] = sum; red[s & 1][1][wv] = sq; }
    __syncthreads();
    float ts = 0.f, tq = 0.f;
    #pragma unroll
    for (int w = 0; w < 6; ++w) { ts += red[s & 1][0][w]; tq += red[s & 1][1][w]; }
    const float mu = ts * (1.f / DI);
    const float var = tq * (1.f / DI) - mu * mu;
    const float rstd = rsqrtf(var + 1e-5f);
    float t = (acc - mu) * rstd * gg + bb2;
    float z = xz[row * 768 + DI + d];
    yg[row * DI + d] = t * (z / (1.f + __expf(-z)));
  }
}

// ---------------------------------------------------------------------------
extern "C" void kernel_launch(void* const* d_in, const int* in_sizes, int n_in,
                              void* d_out, int out_size, void* d_ws, size_t ws_size,
                              hipStream_t stream) {
  const float* x             = (const float*)d_in[0];
  const float* prompt        = (const float*)d_in[1];
  const float* in_proj_w     = (const float*)d_in[2];
  const float* conv_w        = (const float*)d_in[3];
  const float* conv_b        = (const float*)d_in[4];
  const float* x_proj_w      = (const float*)d_in[5];
  const float* dt_proj_w     = (const float*)d_in[6];
  const float* dt_proj_b     = (const float*)d_in[7];
  const float* A_log         = (const float*)d_in[8];
  const float* Dp            = (const float*)d_in[9];
  const float* prompt_proj_w = (const float*)d_in[10];
  const float* ln_g          = (const float*)d_in[11];
  const float* ln_b          = (const float*)d_in[12];
  const float* out_proj_w    = (const float*)d_in[13];
  float* out = (float*)d_out;

  // workspace layout (bytes), total ~79.6 MB
  char* p = (char*)d_ws;
  auto alloc = [&](size_t bytes) { char* r = p; p += (bytes + 255) & ~(size_t)255; return r; };
  float*  xz    = (float*)alloc((size_t)ML * 768 * 4);
  float*  xseq  = (float*)alloc((size_t)ML * DI * 4);
  float*  delta = (float*)alloc((size_t)ML * DI * 4);
  float*  xdbl  = (float*)alloc((size_t)ML * 64 * 4);
  float*  bv    = (float*)alloc((size_t)ML * NS * 4);
  float*  cv    = (float*)alloc((size_t)ML * NS * 4);
  float*  pb    = (float*)alloc((size_t)BB * NC * DI * NS * 4);  // Pb, then hinit (in-place)
  float*  qb    = (float*)alloc((size_t)BB * NC * DI * NS * 4);  // Qb, then yg (reuse)
  ushort* w1h   = (ushort*)alloc((size_t)768 * DM * 2);
  ushort* w1l   = (ushort*)alloc((size_t)768 * DM * 2);
  ushort* w2h   = (ushort*)alloc((size_t)DM * DI * 2);
  ushort* w2l   = (ushort*)alloc((size_t)DM * DI * 2);
  ushort* wxh   = (ushort*)alloc((size_t)64 * DI * 2);
  ushort* wxl   = (ushort*)alloc((size_t)64 * DI * 2);
  float*  yg    = qb;   // Qb dead after scan_combine

  convert_w<<<960, 256, 0, stream>>>(in_proj_w, out_proj_w, x_proj_w,
                                     w1h, w1l, w2h, w2l, wxh, wxl);
  // in_proj: xz = x @ in_proj_w^T   (8192 x 768, K=192)
  gemm_bf16s<128><<<dim3(6, 64), 256, 0, stream>>>(x, w1h, w1l, xz, ML, 768, DM);
  conv_silu<<<(ML * DI) / 256, 256, 0, stream>>>(xz, conv_w, conv_b, xseq);
  // x_dbl = x_seq @ x_proj_w^T (padded to 64 cols, K=384)
  gemm_bf16s<64><<<dim3(1, 64), 256, 0, stream>>>(xseq, wxh, wxl, xdbl, ML, 64, DI);
  finish_kernel<<<ML / 16, 256, 0, stream>>>(xdbl, prompt, dt_proj_w, dt_proj_b,
                                             prompt_proj_w, delta, bv, cv);
  scan_pass1<<<BB * NC, DI, 0, stream>>>(delta, xseq, bv, A_log, pb, qb);
  scan_combine<<<(BB * DI * NS) / 256, 256, 0, stream>>>(pb, qb, pb);  // hinit in-place
  scan_pass2_ln<<<BB * NC, DI, 0, stream>>>(delta, xseq, bv, cv, A_log, Dp,
                                            pb, xz, ln_g, ln_b, yg);
  // out = yg @ out_proj_w^T  (8192 x 192, K=384)
  gemm_bf16s<64><<<dim3(3, 64), 256, 0, stream>>>(yg, w2h, w2l, out, ML, DM, DI);
}

// Round 3
// 186.565 us; speedup vs baseline: 1.2246x; 1.1954x over previous
//
#include <hip/hip_runtime.h>
#include <hip/hip_bf16.h>
#include <math.h>

// Problem constants (fixed by the reference)
#define BB 2
#define HH 64
#define WW 64
#define DM 192            // d_model
#define DI 384            // d_inner
#define NS 16             // d_state
#define RK 12             // dt_rank
#define LL (HH*WW)        // 4096
#define ML (BB*LL)        // 8192 rows
#define NC 256            // scan chunks
#define CL 16             // chunk length; NC*CL == LL

typedef __attribute__((ext_vector_type(8))) short short8v;   // 8 bf16 (4 VGPRs)
typedef __attribute__((ext_vector_type(4))) float f32x4;

__device__ __forceinline__ ushort f2bf(float f) {
  unsigned u = __float_as_uint(f);
  u += 0x7fffu + ((u >> 16) & 1u);          // RNE
  return (ushort)(u >> 16);
}
__device__ __forceinline__ float bf2f(ushort h) {
  return __uint_as_float(((unsigned)h) << 16);
}
__device__ __forceinline__ void split2(float f, ushort& h, ushort& l) {
  h = f2bf(f);
  l = f2bf(f - bf2f(h));                    // residual; h+l ~ f to 2^-17 rel
}

// ---------------------------------------------------------------------------
// prep: split f32 -> (bf16 hi, bf16 lo) for in_proj_w, out_proj_w, x_proj_w
// (zero-padded 44->64 rows), and the activation x itself.
// ---------------------------------------------------------------------------
__global__ __launch_bounds__(256) void prep(
    const float* __restrict__ w1, const float* __restrict__ w2,
    const float* __restrict__ wx, const float* __restrict__ x,
    ushort* __restrict__ w1h, ushort* __restrict__ w1l,
    ushort* __restrict__ w2h, ushort* __restrict__ w2l,
    ushort* __restrict__ wxh, ushort* __restrict__ wxl,
    ushort* __restrict__ xh,  ushort* __restrict__ xl) {
  const int N1 = 768 * DM;        // 147456
  const int N2 = DM * DI;         // 73728
  const int N3 = 64 * DI;         // 24576 (padded)
  const int N4 = ML * DM;         // 1572864
  int i = blockIdx.x * 256 + threadIdx.x;
  ushort h, l;
  if (i < N1) {
    split2(w1[i], h, l); w1h[i] = h; w1l[i] = l;
  } else if (i < N1 + N2) {
    int j = i - N1;
    split2(w2[j], h, l); w2h[j] = h; w2l[j] = l;
  } else if (i < N1 + N2 + N3) {
    int j = i - N1 - N2;
    float v = (j < 44 * DI) ? wx[j] : 0.f;
    split2(v, h, l); wxh[j] = h; wxl[j] = l;
  } else if (i < N1 + N2 + N3 + N4) {
    int j = i - N1 - N2 - N3;
    split2(x[j], h, l); xh[j] = h; xl[j] = l;
  }
}

// ---------------------------------------------------------------------------
// Split-bf16 MFMA GEMM:  C[m,n] = sum_k A[m,k] * W[n,k]
// A, W both pre-split bf16 (hi, lo), row-major NxK.
// C = Ah*Wh + Ah*Wl + Al*Wh  (Al*Wl dropped, ~2^-16 relative)
// 4 waves in a 2x2 grid; wave tile (MR*16) x (NR*16); BM=2*MR*16, BN=2*NR*16.
// mfma_f32_16x16x32_bf16 layouts as verified in round 2.
// ---------------------------------------------------------------------------
template<int BM, int BN, int MR, int NR>
__global__ __launch_bounds__(256) void gemm_sp(
    const ushort* __restrict__ Ah, const ushort* __restrict__ Al,
    const ushort* __restrict__ Wh, const ushort* __restrict__ Wl,
    float* __restrict__ C, int M, int N, int K) {
  constexpr int RS = 40;                 // LDS row stride (bf16) = 32 + 8 pad
  __shared__ __align__(16) ushort sAh[BM * RS];
  __shared__ __align__(16) ushort sAl[BM * RS];
  __shared__ __align__(16) ushort sBh[BN * RS];
  __shared__ __align__(16) ushort sBl[BN * RS];
  const int tid = threadIdx.x;
  const int lane = tid & 63, wid = tid >> 6;
  const int wm = (wid >> 1) * (MR * 16);
  const int wn = (wid & 1) * (NR * 16);
  const int bm = blockIdx.y * BM;
  const int bn = blockIdx.x * BN;
  const int r16 = lane & 15;
  const int kb8 = (lane >> 4) * 8;

  f32x4 acc[MR][NR];
  #pragma unroll
  for (int m = 0; m < MR; ++m)
    #pragma unroll
    for (int n = 0; n < NR; ++n)
      acc[m][n] = (f32x4){0.f, 0.f, 0.f, 0.f};

  for (int k0 = 0; k0 < K; k0 += 32) {
    __syncthreads();   // WAR: previous iteration's fragment reads complete
    for (int i = tid; i < BM * 4; i += 256) {
      int row = i >> 2, kc = (i & 3) << 3;
      *reinterpret_cast<short8v*>(&sAh[row * RS + kc]) =
          *reinterpret_cast<const short8v*>(&Ah[(size_t)(bm + row) * K + k0 + kc]);
      *reinterpret_cast<short8v*>(&sAl[row * RS + kc]) =
          *reinterpret_cast<const short8v*>(&Al[(size_t)(bm + row) * K + k0 + kc]);
    }
    for (int i = tid; i < BN * 4; i += 256) {
      int row = i >> 2, kc = (i & 3) << 3;
      *reinterpret_cast<short8v*>(&sBh[row * RS + kc]) =
          *reinterpret_cast<const short8v*>(&Wh[(size_t)(bn + row) * K + k0 + kc]);
      *reinterpret_cast<short8v*>(&sBl[row * RS + kc]) =
          *reinterpret_cast<const short8v*>(&Wl[(size_t)(bn + row) * K + k0 + kc]);
    }
    __syncthreads();

    short8v ah[MR], al[MR], bh[NR], bl[NR];
    #pragma unroll
    for (int m = 0; m < MR; ++m) {
      int off = (wm + m * 16 + r16) * RS + kb8;
      ah[m] = *reinterpret_cast<const short8v*>(&sAh[off]);
      al[m] = *reinterpret_cast<const short8v*>(&sAl[off]);
    }
    #pragma unroll
    for (int n = 0; n < NR; ++n) {
      int off = (wn + n * 16 + r16) * RS + kb8;
      bh[n] = *reinterpret_cast<const short8v*>(&sBh[off]);
      bl[n] = *reinterpret_cast<const short8v*>(&sBl[off]);
    }
    #pragma unroll
    for (int m = 0; m < MR; ++m)
      #pragma unroll
      for (int n = 0; n < NR; ++n)
        acc[m][n] = __builtin_amdgcn_mfma_f32_16x16x32_bf16(ah[m], bh[n], acc[m][n], 0, 0, 0);
    #pragma unroll
    for (int m = 0; m < MR; ++m)
      #pragma unroll
      for (int n = 0; n < NR; ++n)
        acc[m][n] = __builtin_amdgcn_mfma_f32_16x16x32_bf16(ah[m], bl[n], acc[m][n], 0, 0, 0);
    #pragma unroll
    for (int m = 0; m < MR; ++m)
      #pragma unroll
      for (int n = 0; n < NR; ++n)
        acc[m][n] = __builtin_amdgcn_mfma_f32_16x16x32_bf16(al[m], bh[n], acc[m][n], 0, 0, 0);
  }

  const int cr = (lane >> 4) * 4;
  #pragma unroll
  for (int m = 0; m < MR; ++m)
    #pragma unroll
    for (int n = 0; n < NR; ++n) {
      int row = bm + wm + m * 16 + cr;
      int col = bn + wn + n * 16 + r16;
      #pragma unroll
      for (int r = 0; r < 4; ++r)
        C[(size_t)(row + r) * N + col] = acc[m][n][r];
    }
}

// ---------------------------------------------------------------------------
// Depthwise 3x3 conv (SAME, zero pad) + bias + SiLU. Emits f32 (for the scan)
// and bf16 hi/lo (for the x_dbl GEMM).
// ---------------------------------------------------------------------------
__global__ __launch_bounds__(256) void conv_silu(const float* __restrict__ xz,
                                                 const float* __restrict__ conv_w,
                                                 const float* __restrict__ conv_b,
                                                 float* __restrict__ x_seq,
                                                 ushort* __restrict__ xsh,
                                                 ushort* __restrict__ xsl) {
  int idx = blockIdx.x * 256 + threadIdx.x;   // over ML*DI
  int d = idx % DI;
  int l = (idx / DI) % LL;
  int b = idx / (DI * LL);
  int h = l >> 6, w = l & 63;
  float acc = conv_b[d];
  #pragma unroll
  for (int kh = 0; kh < 3; ++kh) {
    int hh = h + kh - 1;
    if (hh < 0 || hh >= HH) continue;
    #pragma unroll
    for (int kw = 0; kw < 3; ++kw) {
      int ww2 = w + kw - 1;
      if (ww2 < 0 || ww2 >= WW) continue;
      acc = fmaf(xz[((size_t)(b * LL + hh * WW + ww2)) * 768 + d],
                 conv_w[d * 9 + kh * 3 + kw], acc);
    }
  }
  float sv = acc / (1.f + __expf(-acc));      // silu
  x_seq[idx] = sv;
  ushort hh16, ll16;
  split2(sv, hh16, ll16);
  xsh[idx] = hh16; xsl[idx] = ll16;
}

// ---------------------------------------------------------------------------
// finish: per (b,l): delta = softplus(xdbl[:12] @ dt_w^T + 2*dt_b) (faithful
// double-bias), B = xdbl[12:28], C = xdbl[28:44] + prompt @ pw^T.
// 16 rows per block; everything served from LDS.
// ---------------------------------------------------------------------------
__global__ __launch_bounds__(256) void finish_kernel(
    const float* __restrict__ xdbl,          // ML x 64
    const float* __restrict__ prompt,        // ML x 192
    const float* __restrict__ dt_proj_w,     // 384 x 12
    const float* __restrict__ dt_proj_b,     // 384
    const float* __restrict__ prompt_proj_w, // 16 x 192
    float* __restrict__ delta, float* __restrict__ Bv, float* __restrict__ Cv) {
  __shared__ float xd[16][64];
  __shared__ float pr[16][193];
  __shared__ float pw[16][193];
  __shared__ float sdt[12][384];
  __shared__ float sdb[384];
  const int tid = threadIdx.x;
  const size_t l0 = (size_t)blockIdx.x * 16;

  {  // xd: 16x64 = 256 float4, one per thread
    int r = tid >> 4, c4 = (tid & 15) << 2;
    float4 v = *reinterpret_cast<const float4*>(&xdbl[(l0 + r) * 64 + c4]);
    xd[r][c4] = v.x; xd[r][c4+1] = v.y; xd[r][c4+2] = v.z; xd[r][c4+3] = v.w;
  }
  for (int i = tid; i < 768; i += 256) {   // prompt rows 16x192
    int r = i / 48, c4 = (i % 48) << 2;
    float4 v = *reinterpret_cast<const float4*>(&prompt[(l0 + r) * DM + c4]);
    pr[r][c4] = v.x; pr[r][c4+1] = v.y; pr[r][c4+2] = v.z; pr[r][c4+3] = v.w;
  }
  for (int i = tid; i < 768; i += 256) {   // prompt_proj_w 16x192
    int r = i / 48, c4 = (i % 48) << 2;
    float4 v = *reinterpret_cast<const float4*>(&prompt_proj_w[r * DM + c4]);
    pw[r][c4] = v.x; pw[r][c4+1] = v.y; pw[r][c4+2] = v.z; pw[r][c4+3] = v.w;
  }
  for (int i = tid; i < DI * RK; i += 256)  // dt_proj_w transposed
    sdt[i % RK][i / RK] = dt_proj_w[i];
  for (int i = tid; i < DI; i += 256)
    sdb[i] = 2.0f * dt_proj_b[i];           // bias applied twice (faithful)
  __syncthreads();

  // delta
  for (int o = tid; o < 16 * DI; o += 256) {
    int r = o / DI, dd = o % DI;
    float acc = sdb[dd];
    #pragma unroll
    for (int j = 0; j < RK; ++j) acc = fmaf(xd[r][j], sdt[j][dd], acc);
    float sp = fmaxf(acc, 0.f) + log1pf(__expf(-fabsf(acc)));  // softplus
    delta[(l0 + r) * DI + dd] = sp;
  }
  // B and C (exactly 256 outputs; lanes n-fast for coalesced writes)
  {
    int r = tid >> 4, n = tid & 15;
    Bv[(l0 + r) * NS + n] = xd[r][12 + n];
    float acc = xd[r][28 + n];
    for (int c = 0; c < DM; ++c) acc = fmaf(pr[r][c], pw[n][c], acc);
    Cv[(l0 + r) * NS + n] = acc;
  }
}

// ---------------------------------------------------------------------------
// Chunked scan pass 1: per (b, chunk, d) compute P_n = prod(dA), Q_n = local h.
// ---------------------------------------------------------------------------
__global__ __launch_bounds__(DI) void scan_pass1(const float* __restrict__ delta,
                                                 const float* __restrict__ x_seq,
                                                 const float* __restrict__ Bv,
                                                 const float* __restrict__ A_log,
                                                 float* __restrict__ Pb,
                                                 float* __restrict__ Qb) {
  const int d = threadIdx.x;
  const int c = blockIdx.x & (NC - 1);
  const int b = blockIdx.x >> 8;            // NC == 256
  __shared__ float sB[CL][NS];
  for (int idx = threadIdx.x; idx < CL * NS; idx += DI)
    sB[idx >> 4][idx & 15] = Bv[(size_t)(b * LL + c * CL) * NS + idx];

  float a2[NS], h[NS], p[NS];
  #pragma unroll
  for (int n = 0; n < NS; ++n) {
    a2[n] = -__expf(A_log[d * NS + n]) * 1.4426950408889634f;  // A * log2(e)
    h[n] = 0.f; p[n] = 1.f;
  }
  __syncthreads();

  const size_t rowbase = (size_t)(b * LL + c * CL) * DI + d;
  for (int s = 0; s < CL; ++s) {
    float de = delta[rowbase + (size_t)s * DI];
    float du = de * x_seq[rowbase + (size_t)s * DI];
    #pragma unroll
    for (int n = 0; n < NS; ++n) {
      float e = exp2f(de * a2[n]);
      h[n] = fmaf(e, h[n], du * sB[s][n]);
      p[n] *= e;
    }
  }
  const size_t base = ((size_t)(b * NC + c) * DI + d) * NS;
  #pragma unroll
  for (int n = 0; n < NS; n += 4) {
    *reinterpret_cast<float4*>(&Pb[base + n]) = make_float4(p[n], p[n+1], p[n+2], p[n+3]);
    *reinterpret_cast<float4*>(&Qb[base + n]) = make_float4(h[n], h[n+1], h[n+2], h[n+3]);
  }
}

// ---------------------------------------------------------------------------
// Combine chunk states: per (b,d,n) scan over NC chunks, 8-deep prefetch.
// ---------------------------------------------------------------------------
__global__ __launch_bounds__(256) void scan_combine(const float* __restrict__ Pb,
                                                    const float* __restrict__ Qb,
                                                    float* __restrict__ Hout) {
  const int t = blockIdx.x * 256 + threadIdx.x;   // 12288 total
  const int b = t / (DI * NS);
  const int dn = t % (DI * NS);
  const size_t S = DI * NS;
  const size_t base = (size_t)b * NC * S + dn;
  float h = 0.f;
  float P[8], Q[8];
  #pragma unroll
  for (int j = 0; j < 8; ++j) { P[j] = Pb[base + (size_t)j * S]; Q[j] = Qb[base + (size_t)j * S]; }
  for (int c0 = 0; c0 < NC; c0 += 8) {
    float P2[8] = {0,0,0,0,0,0,0,0}, Q2[8] = {0,0,0,0,0,0,0,0};
    if (c0 + 8 < NC) {
      #pragma unroll
      for (int j = 0; j < 8; ++j) {
        P2[j] = Pb[base + (size_t)(c0 + 8 + j) * S];
        Q2[j] = Qb[base + (size_t)(c0 + 8 + j) * S];
      }
    }
    #pragma unroll
    for (int j = 0; j < 8; ++j) {
      Hout[base + (size_t)(c0 + j) * S] = h;
      h = fmaf(P[j], h, Q[j]);
    }
    #pragma unroll
    for (int j = 0; j < 8; ++j) { P[j] = P2[j]; Q[j] = Q2[j]; }
  }
}

// ---------------------------------------------------------------------------
// Pass 2 + fused LayerNorm + SiLU gate. Block = 384 threads (one per d),
// CL=16 rows per block. Emits yg as pre-split bf16 hi/lo for out_proj.
// ---------------------------------------------------------------------------
__global__ __launch_bounds__(DI) void scan_pass2_ln(
    const float* __restrict__ delta, const float* __restrict__ x_seq,
    const float* __restrict__ Bv, const float* __restrict__ Cv,
    const float* __restrict__ A_log, const float* __restrict__ Dp,
    const float* __restrict__ hin, const float* __restrict__ xz,
    const float* __restrict__ ln_g, const float* __restrict__ ln_b,
    ushort* __restrict__ ygh, ushort* __restrict__ ygl) {
  const int d = threadIdx.x;
  const int c = blockIdx.x & (NC - 1);
  const int b = blockIdx.x >> 8;
  __shared__ float sB[CL][NS], sC[CL][NS];
  __shared__ float red[2][2][6];
  for (int idx = threadIdx.x; idx < CL * NS; idx += DI) {
    size_t g = (size_t)(b * LL + c * CL) * NS + idx;
    sB[idx >> 4][idx & 15] = Bv[g];
    sC[idx >> 4][idx & 15] = Cv[g];
  }
  float a2[NS], h[NS];
  const size_t hbase = ((size_t)(b * NC + c) * DI + d) * NS;
  #pragma unroll
  for (int n = 0; n < NS; n += 4) {
    float4 hv = *reinterpret_cast<const float4*>(&hin[hbase + n]);
    h[n] = hv.x; h[n+1] = hv.y; h[n+2] = hv.z; h[n+3] = hv.w;
  }
  #pragma unroll
  for (int n = 0; n < NS; ++n)
    a2[n] = -__expf(A_log[d * NS + n]) * 1.4426950408889634f;
  const float Dd = Dp[d];
  const float gg = ln_g[d], bb2 = ln_b[d];
  const int wv = d >> 6, ln0 = d & 63;
  __syncthreads();

  const size_t row0 = (size_t)(b * LL + c * CL);
  for (int s = 0; s < CL; ++s) {
    const size_t row = row0 + s;
    float de = delta[row * DI + d];
    float u  = x_seq[row * DI + d];
    float du = de * u;
    float acc = Dd * u;
    #pragma unroll
    for (int n = 0; n < NS; ++n) {
      float e = exp2f(de * a2[n]);
      h[n] = fmaf(e, h[n], du * sB[s][n]);
      acc = fmaf(h[n], sC[s][n], acc);
    }
    // block LayerNorm over 384 threads
    float sum = acc, sq = acc * acc;
    #pragma unroll
    for (int off = 32; off >= 1; off >>= 1) {
      sum += __shfl_xor(sum, off, 64);
      sq  += __shfl_xor(sq,  off, 64);
    }
    if (ln0 == 0) { red[s & 1][0][wv] = sum; red[s & 1][1][wv] = sq; }
    __syncthreads();
    float ts = 0.f, tq = 0.f;
    #pragma unroll
    for (int w = 0; w < 6; ++w) { ts += red[s & 1][0][w]; tq += red[s & 1][1][w]; }
    const float mu = ts * (1.f / DI);
    const float var = tq * (1.f / DI) - mu * mu;
    const float rstd = rsqrtf(var + 1e-5f);
    float t = (acc - mu) * rstd * gg + bb2;
    float z = xz[row * 768 + DI + d];
    float outv = t * (z / (1.f + __expf(-z)));
    ushort hh16, ll16;
    split2(outv, hh16, ll16);
    ygh[row * DI + d] = hh16;
    ygl[row * DI + d] = ll16;
  }
}

// ---------------------------------------------------------------------------
extern "C" void kernel_launch(void* const* d_in, const int* in_sizes, int n_in,
                              void* d_out, int out_size, void* d_ws, size_t ws_size,
                              hipStream_t stream) {
  const float* x             = (const float*)d_in[0];
  const float* prompt        = (const float*)d_in[1];
  const float* in_proj_w     = (const float*)d_in[2];
  const float* conv_w        = (const float*)d_in[3];
  const float* conv_b        = (const float*)d_in[4];
  const float* x_proj_w      = (const float*)d_in[5];
  const float* dt_proj_w     = (const float*)d_in[6];
  const float* dt_proj_b     = (const float*)d_in[7];
  const float* A_log         = (const float*)d_in[8];
  const float* Dp            = (const float*)d_in[9];
  const float* prompt_proj_w = (const float*)d_in[10];
  const float* ln_g          = (const float*)d_in[11];
  const float* ln_b          = (const float*)d_in[12];
  const float* out_proj_w    = (const float*)d_in[13];
  float* out = (float*)d_out;

  // workspace layout (bytes), total ~136 MB (ws is 256 MiB)
  char* p = (char*)d_ws;
  auto alloc = [&](size_t bytes) { char* r = p; p += (bytes + 255) & ~(size_t)255; return r; };
  float*  xz    = (float*)alloc((size_t)ML * 768 * 4);
  float*  xseq  = (float*)alloc((size_t)ML * DI * 4);
  float*  delta = (float*)alloc((size_t)ML * DI * 4);
  float*  xdbl  = (float*)alloc((size_t)ML * 64 * 4);
  float*  bv    = (float*)alloc((size_t)ML * NS * 4);
  float*  cv    = (float*)alloc((size_t)ML * NS * 4);
  float*  pb    = (float*)alloc((size_t)BB * NC * DI * NS * 4);
  float*  qb    = (float*)alloc((size_t)BB * NC * DI * NS * 4);
  float*  hin   = (float*)alloc((size_t)BB * NC * DI * NS * 4);
  ushort* w1h   = (ushort*)alloc((size_t)768 * DM * 2);
  ushort* w1l   = (ushort*)alloc((size_t)768 * DM * 2);
  ushort* w2h   = (ushort*)alloc((size_t)DM * DI * 2);
  ushort* w2l   = (ushort*)alloc((size_t)DM * DI * 2);
  ushort* wxh   = (ushort*)alloc((size_t)64 * DI * 2);
  ushort* wxl   = (ushort*)alloc((size_t)64 * DI * 2);
  ushort* xh    = (ushort*)alloc((size_t)ML * DM * 2);
  ushort* xl    = (ushort*)alloc((size_t)ML * DM * 2);
  ushort* xsh   = (ushort*)alloc((size_t)ML * DI * 2);
  ushort* xsl   = (ushort*)alloc((size_t)ML * DI * 2);
  ushort* ygh   = (ushort*)alloc((size_t)ML * DI * 2);
  ushort* ygl   = (ushort*)alloc((size_t)ML * DI * 2);

  prep<<<7104, 256, 0, stream>>>(in_proj_w, out_proj_w, x_proj_w, x,
                                 w1h, w1l, w2h, w2l, wxh, wxl, xh, xl);
  // in_proj: xz = x @ in_proj_w^T   (8192 x 768, K=192); 512 blocks
  gemm_sp<128, 96, 4, 3><<<dim3(8, 64), 256, 0, stream>>>(xh, xl, w1h, w1l, xz, ML, 768, DM);
  conv_silu<<<(ML * DI) / 256, 256, 0, stream>>>(xz, conv_w, conv_b, xseq, xsh, xsl);
  // x_dbl = x_seq @ x_proj_w^T (padded to 64 cols, K=384); 256 blocks
  gemm_sp<32, 64, 1, 2><<<dim3(1, 256), 256, 0, stream>>>(xsh, xsl, wxh, wxl, xdbl, ML, 64, DI);
  finish_kernel<<<ML / 16, 256, 0, stream>>>(xdbl, prompt, dt_proj_w, dt_proj_b,
                                             prompt_proj_w, delta, bv, cv);
  scan_pass1<<<BB * NC, DI, 0, stream>>>(delta, xseq, bv, A_log, pb, qb);
  scan_combine<<<(BB * DI * NS) / 256, 256, 0, stream>>>(pb, qb, hin);
  scan_pass2_ln<<<BB * NC, DI, 0, stream>>>(delta, xseq, bv, cv, A_log, Dp,
                                            hin, xz, ln_g, ln_b, ygh, ygl);
  // out = yg @ out_proj_w^T  (8192 x 192, K=384); 384 blocks
  gemm_sp<64, 64, 2, 2><<<dim3(3, 128), 256, 0, stream>>>(ygh, ygl, w2h, w2l, out, ML, DM, DI);
}

// Round 4
// 159.047 us; speedup vs baseline: 1.4365x; 1.1730x over previous
//
#include <hip/hip_runtime.h>
#include <hip/hip_bf16.h>
#include <math.h>

// Problem constants (fixed by the reference)
#define BB 2
#define HH 64
#define WW 64
#define DM 192            // d_model
#define DI 384            // d_inner
#define NS 16             // d_state
#define RK 12             // dt_rank
#define LL (HH*WW)        // 4096
#define ML (BB*LL)        // 8192 rows
#define NC 256            // scan chunks
#define CL 16             // chunk length; NC*CL == LL

typedef __attribute__((ext_vector_type(8))) short short8v;   // 8 bf16 (4 VGPRs)
typedef __attribute__((ext_vector_type(4))) float f32x4;

__device__ __forceinline__ ushort f2bf(float f) {
  unsigned u = __float_as_uint(f);
  u += 0x7fffu + ((u >> 16) & 1u);          // RNE
  return (ushort)(u >> 16);
}
__device__ __forceinline__ float bf2f(ushort h) {
  return __uint_as_float(((unsigned)h) << 16);
}
__device__ __forceinline__ void split2(float f, ushort& h, ushort& l) {
  h = f2bf(f);
  l = f2bf(f - bf2f(h));                    // residual; h+l ~ f to 2^-17 rel
}

// ---------------------------------------------------------------------------
// prep (vectorized x4): split f32 -> (bf16 hi, bf16 lo) for in_proj_w,
// out_proj_w, x_proj_w (zero-padded 44->64 rows), the activation x; plus a
// scalar tail that transposes conv_w [384][9] -> conv_wt [9][384].
// ---------------------------------------------------------------------------
__global__ __launch_bounds__(256) void prep(
    const float* __restrict__ w1, const float* __restrict__ w2,
    const float* __restrict__ wx, const float* __restrict__ x,
    const float* __restrict__ conv_w,
    ushort* __restrict__ w1h, ushort* __restrict__ w1l,
    ushort* __restrict__ w2h, ushort* __restrict__ w2l,
    ushort* __restrict__ wxh, ushort* __restrict__ wxl,
    ushort* __restrict__ xh,  ushort* __restrict__ xl,
    float* __restrict__ conv_wt) {
  const int Q1 = 768 * DM / 4;       // 36864
  const int Q2 = DM * DI / 4;        // 18432
  const int Q3 = 64 * DI / 4;        // 6144 (padded region)
  const int Q4 = ML * DM / 4;        // 393216
  const int QT = Q1 + Q2 + Q3 + Q4;  // 454656
  int i = blockIdx.x * 256 + threadIdx.x;
  if (i < QT) {
    const float* src; ushort* dh; ushort* dl; int j;
    if (i < Q1)                { src = w1; dh = w1h; dl = w1l; j = i; }
    else if (i < Q1 + Q2)      { src = w2; dh = w2h; dl = w2l; j = i - Q1; }
    else if (i < Q1 + Q2 + Q3) { src = wx; dh = wxh; dl = wxl; j = i - Q1 - Q2; }
    else                       { src = x;  dh = xh;  dl = xl;  j = i - Q1 - Q2 - Q3; }
    float4 v;
    if (dh == wxh && j * 4 >= 44 * DI) v = make_float4(0.f, 0.f, 0.f, 0.f);
    else v = *reinterpret_cast<const float4*>(&src[(size_t)j * 4]);
    ushort4 h, l;
    split2(v.x, h.x, l.x); split2(v.y, h.y, l.y);
    split2(v.z, h.z, l.z); split2(v.w, h.w, l.w);
    *reinterpret_cast<ushort4*>(&dh[(size_t)j * 4]) = h;
    *reinterpret_cast<ushort4*>(&dl[(size_t)j * 4]) = l;
  } else if (i < QT + DI * 9) {
    int ct = i - QT;                 // over 3456
    int k = ct % 9, d = ct / 9;
    conv_wt[k * DI + d] = conv_w[ct];
  }
}

// ---------------------------------------------------------------------------
// Split-bf16 MFMA GEMM:  C[m,n] = sum_k A[m,k] * W[n,k]
// A, W both pre-split bf16 (hi, lo), row-major NxK.
// C = Ah*Wh + Ah*Wl + Al*Wh  (Al*Wl dropped, ~2^-16 relative)
// 4 waves in a 2x2 grid; wave tile (MR*16) x (NR*16); BM=2*MR*16, BN=2*NR*16.
// ---------------------------------------------------------------------------
template<int BM, int BN, int MR, int NR>
__global__ __launch_bounds__(256) void gemm_sp(
    const ushort* __restrict__ Ah, const ushort* __restrict__ Al,
    const ushort* __restrict__ Wh, const ushort* __restrict__ Wl,
    float* __restrict__ C, int M, int N, int K) {
  constexpr int RS = 40;                 // LDS row stride (bf16) = 32 + 8 pad
  __shared__ __align__(16) ushort sAh[BM * RS];
  __shared__ __align__(16) ushort sAl[BM * RS];
  __shared__ __align__(16) ushort sBh[BN * RS];
  __shared__ __align__(16) ushort sBl[BN * RS];
  const int tid = threadIdx.x;
  const int lane = tid & 63, wid = tid >> 6;
  const int wm = (wid >> 1) * (MR * 16);
  const int wn = (wid & 1) * (NR * 16);
  const int bm = blockIdx.y * BM;
  const int bn = blockIdx.x * BN;
  const int r16 = lane & 15;
  const int kb8 = (lane >> 4) * 8;

  f32x4 acc[MR][NR];
  #pragma unroll
  for (int m = 0; m < MR; ++m)
    #pragma unroll
    for (int n = 0; n < NR; ++n)
      acc[m][n] = (f32x4){0.f, 0.f, 0.f, 0.f};

  for (int k0 = 0; k0 < K; k0 += 32) {
    __syncthreads();   // WAR: previous iteration's fragment reads complete
    for (int i = tid; i < BM * 4; i += 256) {
      int row = i >> 2, kc = (i & 3) << 3;
      *reinterpret_cast<short8v*>(&sAh[row * RS + kc]) =
          *reinterpret_cast<const short8v*>(&Ah[(size_t)(bm + row) * K + k0 + kc]);
      *reinterpret_cast<short8v*>(&sAl[row * RS + kc]) =
          *reinterpret_cast<const short8v*>(&Al[(size_t)(bm + row) * K + k0 + kc]);
    }
    for (int i = tid; i < BN * 4; i += 256) {
      int row = i >> 2, kc = (i & 3) << 3;
      *reinterpret_cast<short8v*>(&sBh[row * RS + kc]) =
          *reinterpret_cast<const short8v*>(&Wh[(size_t)(bn + row) * K + k0 + kc]);
      *reinterpret_cast<short8v*>(&sBl[row * RS + kc]) =
          *reinterpret_cast<const short8v*>(&Wl[(size_t)(bn + row) * K + k0 + kc]);
    }
    __syncthreads();

    short8v ah[MR], al[MR], bh[NR], bl[NR];
    #pragma unroll
    for (int m = 0; m < MR; ++m) {
      int off = (wm + m * 16 + r16) * RS + kb8;
      ah[m] = *reinterpret_cast<const short8v*>(&sAh[off]);
      al[m] = *reinterpret_cast<const short8v*>(&sAl[off]);
    }
    #pragma unroll
    for (int n = 0; n < NR; ++n) {
      int off = (wn + n * 16 + r16) * RS + kb8;
      bh[n] = *reinterpret_cast<const short8v*>(&sBh[off]);
      bl[n] = *reinterpret_cast<const short8v*>(&sBl[off]);
    }
    #pragma unroll
    for (int m = 0; m < MR; ++m)
      #pragma unroll
      for (int n = 0; n < NR; ++n)
        acc[m][n] = __builtin_amdgcn_mfma_f32_16x16x32_bf16(ah[m], bh[n], acc[m][n], 0, 0, 0);
    #pragma unroll
    for (int m = 0; m < MR; ++m)
      #pragma unroll
      for (int n = 0; n < NR; ++n)
        acc[m][n] = __builtin_amdgcn_mfma_f32_16x16x32_bf16(ah[m], bl[n], acc[m][n], 0, 0, 0);
    #pragma unroll
    for (int m = 0; m < MR; ++m)
      #pragma unroll
      for (int n = 0; n < NR; ++n)
        acc[m][n] = __builtin_amdgcn_mfma_f32_16x16x32_bf16(al[m], bh[n], acc[m][n], 0, 0, 0);
  }

  const int cr = (lane >> 4) * 4;
  #pragma unroll
  for (int m = 0; m < MR; ++m)
    #pragma unroll
    for (int n = 0; n < NR; ++n) {
      int row = bm + wm + m * 16 + cr;
      int col = bn + wn + n * 16 + r16;
      #pragma unroll
      for (int r = 0; r < 4; ++r)
        C[(size_t)(row + r) * N + col] = acc[m][n][r];
    }
}

// ---------------------------------------------------------------------------
// Depthwise 3x3 conv (SAME) + bias + SiLU, vectorized x4 over d.
// Uses transposed weights conv_wt [9][384] for float4 loads.
// ---------------------------------------------------------------------------
__global__ __launch_bounds__(256) void conv_silu(const float* __restrict__ xz,
                                                 const float* __restrict__ conv_wt,
                                                 const float* __restrict__ conv_b,
                                                 float* __restrict__ x_seq,
                                                 ushort* __restrict__ xsh,
                                                 ushort* __restrict__ xsl) {
  int t = blockIdx.x * 256 + threadIdx.x;      // over ML*DI/4
  int d4 = (t % (DI / 4)) * 4;
  int l  = (t / (DI / 4)) % LL;
  int b  = t / ((DI / 4) * LL);
  int h = l >> 6, w = l & 63;
  float4 acc = *reinterpret_cast<const float4*>(&conv_b[d4]);
  #pragma unroll
  for (int kh = 0; kh < 3; ++kh) {
    int hh = h + kh - 1;
    if (hh < 0 || hh >= HH) continue;
    #pragma unroll
    for (int kw = 0; kw < 3; ++kw) {
      int ww2 = w + kw - 1;
      if (ww2 < 0 || ww2 >= WW) continue;
      float4 v = *reinterpret_cast<const float4*>(
          &xz[((size_t)(b * LL + hh * WW + ww2)) * 768 + d4]);
      float4 wv = *reinterpret_cast<const float4*>(&conv_wt[(kh * 3 + kw) * DI + d4]);
      acc.x = fmaf(v.x, wv.x, acc.x); acc.y = fmaf(v.y, wv.y, acc.y);
      acc.z = fmaf(v.z, wv.z, acc.z); acc.w = fmaf(v.w, wv.w, acc.w);
    }
  }
  float4 sv;
  sv.x = acc.x / (1.f + __expf(-acc.x));
  sv.y = acc.y / (1.f + __expf(-acc.y));
  sv.z = acc.z / (1.f + __expf(-acc.z));
  sv.w = acc.w / (1.f + __expf(-acc.w));
  size_t o = (size_t)t * 4;
  *reinterpret_cast<float4*>(&x_seq[o]) = sv;
  ushort4 hh4, ll4;
  split2(sv.x, hh4.x, ll4.x); split2(sv.y, hh4.y, ll4.y);
  split2(sv.z, hh4.z, ll4.z); split2(sv.w, hh4.w, ll4.w);
  *reinterpret_cast<ushort4*>(&xsh[o]) = hh4;
  *reinterpret_cast<ushort4*>(&xsl[o]) = ll4;
}

// ---------------------------------------------------------------------------
// finish: per (b,l): delta = softplus(xdbl[:12] @ dt_w^T + 2*dt_b) (faithful
// double-bias), B = xdbl[12:28], C = xdbl[28:44] + prompt @ pw^T.
// ---------------------------------------------------------------------------
__global__ __launch_bounds__(256) void finish_kernel(
    const float* __restrict__ xdbl,          // ML x 64
    const float* __restrict__ prompt,        // ML x 192
    const float* __restrict__ dt_proj_w,     // 384 x 12
    const float* __restrict__ dt_proj_b,     // 384
    const float* __restrict__ prompt_proj_w, // 16 x 192
    float* __restrict__ delta, float* __restrict__ Bv, float* __restrict__ Cv) {
  __shared__ float xd[16][64];
  __shared__ float pr[16][193];
  __shared__ float pw[16][193];
  __shared__ float sdt[12][384];
  __shared__ float sdb[384];
  const int tid = threadIdx.x;
  const size_t l0 = (size_t)blockIdx.x * 16;

  {  // xd: 16x64 = 256 float4, one per thread
    int r = tid >> 4, c4 = (tid & 15) << 2;
    float4 v = *reinterpret_cast<const float4*>(&xdbl[(l0 + r) * 64 + c4]);
    xd[r][c4] = v.x; xd[r][c4+1] = v.y; xd[r][c4+2] = v.z; xd[r][c4+3] = v.w;
  }
  for (int i = tid; i < 768; i += 256) {   // prompt rows 16x192
    int r = i / 48, c4 = (i % 48) << 2;
    float4 v = *reinterpret_cast<const float4*>(&prompt[(l0 + r) * DM + c4]);
    pr[r][c4] = v.x; pr[r][c4+1] = v.y; pr[r][c4+2] = v.z; pr[r][c4+3] = v.w;
  }
  for (int i = tid; i < 768; i += 256) {   // prompt_proj_w 16x192
    int r = i / 48, c4 = (i % 48) << 2;
    float4 v = *reinterpret_cast<const float4*>(&prompt_proj_w[r * DM + c4]);
    pw[r][c4] = v.x; pw[r][c4+1] = v.y; pw[r][c4+2] = v.z; pw[r][c4+3] = v.w;
  }
  for (int i = tid; i < DI * RK; i += 256)  // dt_proj_w transposed
    sdt[i % RK][i / RK] = dt_proj_w[i];
  for (int i = tid; i < DI; i += 256)
    sdb[i] = 2.0f * dt_proj_b[i];           // bias applied twice (faithful)
  __syncthreads();

  // delta
  for (int o = tid; o < 16 * DI; o += 256) {
    int r = o / DI, dd = o % DI;
    float acc = sdb[dd];
    #pragma unroll
    for (int j = 0; j < RK; ++j) acc = fmaf(xd[r][j], sdt[j][dd], acc);
    float sp = fmaxf(acc, 0.f) + log1pf(__expf(-fabsf(acc)));  // softplus
    delta[(l0 + r) * DI + dd] = sp;
  }
  // B and C (exactly 256 outputs; lanes n-fast for coalesced writes)
  {
    int r = tid >> 4, n = tid & 15;
    Bv[(l0 + r) * NS + n] = xd[r][12 + n];
    float acc = xd[r][28 + n];
    for (int c = 0; c < DM; ++c) acc = fmaf(pr[r][c], pw[n][c], acc);
    Cv[(l0 + r) * NS + n] = acc;
  }
}

// ---------------------------------------------------------------------------
// Chunked scan pass 1: per (b, chunk, d) compute P_n = prod(dA), Q_n = local h.
// All CL inputs prefetched to registers before the recurrence (latency fix).
// ---------------------------------------------------------------------------
__global__ __launch_bounds__(DI) void scan_pass1(const float* __restrict__ delta,
                                                 const float* __restrict__ x_seq,
                                                 const float* __restrict__ Bv,
                                                 const float* __restrict__ A_log,
                                                 float* __restrict__ Pb,
                                                 float* __restrict__ Qb) {
  const int d = threadIdx.x;
  const int c = blockIdx.x & (NC - 1);
  const int b = blockIdx.x >> 8;            // NC == 256
  __shared__ float sB[CL][NS];
  for (int idx = threadIdx.x; idx < CL * NS; idx += DI)
    sB[idx >> 4][idx & 15] = Bv[(size_t)(b * LL + c * CL) * NS + idx];

  const size_t rowbase = (size_t)(b * LL + c * CL) * DI + d;
  float dlt[CL], xu[CL];
  #pragma unroll
  for (int s = 0; s < CL; ++s) dlt[s] = delta[rowbase + (size_t)s * DI];
  #pragma unroll
  for (int s = 0; s < CL; ++s) xu[s]  = x_seq[rowbase + (size_t)s * DI];

  float a2[NS], h[NS], p[NS];
  #pragma unroll
  for (int n = 0; n < NS; n += 4) {
    float4 av = *reinterpret_cast<const float4*>(&A_log[d * NS + n]);
    a2[n+0] = -__expf(av.x) * 1.4426950408889634f;
    a2[n+1] = -__expf(av.y) * 1.4426950408889634f;
    a2[n+2] = -__expf(av.z) * 1.4426950408889634f;
    a2[n+3] = -__expf(av.w) * 1.4426950408889634f;
  }
  #pragma unroll
  for (int n = 0; n < NS; ++n) { h[n] = 0.f; p[n] = 1.f; }
  __syncthreads();

  #pragma unroll
  for (int s = 0; s < CL; ++s) {
    float de = dlt[s];
    float du = de * xu[s];
    #pragma unroll
    for (int n = 0; n < NS; ++n) {
      float e = exp2f(de * a2[n]);
      h[n] = fmaf(e, h[n], du * sB[s][n]);
      p[n] *= e;
    }
  }
  const size_t base = ((size_t)(b * NC + c) * DI + d) * NS;
  #pragma unroll
  for (int n = 0; n < NS; n += 4) {
    *reinterpret_cast<float4*>(&Pb[base + n]) = make_float4(p[n], p[n+1], p[n+2], p[n+3]);
    *reinterpret_cast<float4*>(&Qb[base + n]) = make_float4(h[n], h[n+1], h[n+2], h[n+3]);
  }
}

// ---------------------------------------------------------------------------
// Combine chunk states: per (b,d,n) scan over NC chunks, 8-deep prefetch.
// ---------------------------------------------------------------------------
__global__ __launch_bounds__(256) void scan_combine(const float* __restrict__ Pb,
                                                    const float* __restrict__ Qb,
                                                    float* __restrict__ Hout) {
  const int t = blockIdx.x * 256 + threadIdx.x;   // 12288 total
  const int b = t / (DI * NS);
  const int dn = t % (DI * NS);
  const size_t S = DI * NS;
  const size_t base = (size_t)b * NC * S + dn;
  float h = 0.f;
  float P[8], Q[8];
  #pragma unroll
  for (int j = 0; j < 8; ++j) { P[j] = Pb[base + (size_t)j * S]; Q[j] = Qb[base + (size_t)j * S]; }
  for (int c0 = 0; c0 < NC; c0 += 8) {
    float P2[8] = {0,0,0,0,0,0,0,0}, Q2[8] = {0,0,0,0,0,0,0,0};
    if (c0 + 8 < NC) {
      #pragma unroll
      for (int j = 0; j < 8; ++j) {
        P2[j] = Pb[base + (size_t)(c0 + 8 + j) * S];
        Q2[j] = Qb[base + (size_t)(c0 + 8 + j) * S];
      }
    }
    #pragma unroll
    for (int j = 0; j < 8; ++j) {
      Hout[base + (size_t)(c0 + j) * S] = h;
      h = fmaf(P[j], h, Q[j]);
    }
    #pragma unroll
    for (int j = 0; j < 8; ++j) { P[j] = P2[j]; Q[j] = Q2[j]; }
  }
}

// ---------------------------------------------------------------------------
// Pass 2 + fused LN + SiLU gate, restructured:
//  phase 1: barrier-free recurrence (all inputs prefetched), acc -> LDS sY
//  phase 2: one barrier, then wave-per-row LN (shuffle reduce, no block sync)
// ---------------------------------------------------------------------------
__global__ __launch_bounds__(DI) void scan_pass2_ln(
    const float* __restrict__ delta, const float* __restrict__ x_seq,
    const float* __restrict__ Bv, const float* __restrict__ Cv,
    const float* __restrict__ A_log, const float* __restrict__ Dp,
    const float* __restrict__ hin, const float* __restrict__ xz,
    const float* __restrict__ ln_g, const float* __restrict__ ln_b,
    ushort* __restrict__ ygh, ushort* __restrict__ ygl) {
  const int d = threadIdx.x;
  const int c = blockIdx.x & (NC - 1);
  const int b = blockIdx.x >> 8;
  __shared__ float sB[CL][NS], sC[CL][NS];
  __shared__ float sY[CL][DI + 1];
  for (int idx = threadIdx.x; idx < CL * NS; idx += DI) {
    size_t g = (size_t)(b * LL + c * CL) * NS + idx;
    sB[idx >> 4][idx & 15] = Bv[g];
    sC[idx >> 4][idx & 15] = Cv[g];
  }
  const size_t row0 = (size_t)(b * LL + c * CL);
  const size_t rowbase = row0 * DI + d;
  float dlt[CL], xu[CL];
  #pragma unroll
  for (int s = 0; s < CL; ++s) dlt[s] = delta[rowbase + (size_t)s * DI];
  #pragma unroll
  for (int s = 0; s < CL; ++s) xu[s]  = x_seq[rowbase + (size_t)s * DI];

  float a2[NS], h[NS];
  const size_t hbase = ((size_t)(b * NC + c) * DI + d) * NS;
  #pragma unroll
  for (int n = 0; n < NS; n += 4) {
    float4 hv = *reinterpret_cast<const float4*>(&hin[hbase + n]);
    h[n] = hv.x; h[n+1] = hv.y; h[n+2] = hv.z; h[n+3] = hv.w;
  }
  #pragma unroll
  for (int n = 0; n < NS; n += 4) {
    float4 av = *reinterpret_cast<const float4*>(&A_log[d * NS + n]);
    a2[n+0] = -__expf(av.x) * 1.4426950408889634f;
    a2[n+1] = -__expf(av.y) * 1.4426950408889634f;
    a2[n+2] = -__expf(av.z) * 1.4426950408889634f;
    a2[n+3] = -__expf(av.w) * 1.4426950408889634f;
  }
  const float Dd = Dp[d];
  __syncthreads();

  // phase 1: recurrence, no barriers
  #pragma unroll
  for (int s = 0; s < CL; ++s) {
    float de = dlt[s];
    float u  = xu[s];
    float du = de * u;
    float acc = Dd * u;
    #pragma unroll
    for (int n = 0; n < NS; ++n) {
      float e = exp2f(de * a2[n]);
      h[n] = fmaf(e, h[n], du * sB[s][n]);
      acc = fmaf(h[n], sC[s][n], acc);
    }
    sY[s][d] = acc;
  }
  __syncthreads();

  // phase 2: wave-per-row LayerNorm + gate + bf16 split
  const int wv = d >> 6, lane = d & 63;
  for (int r = wv; r < CL; r += 6) {
    const size_t row = row0 + r;
    float v[6];
    float sum = 0.f, sq = 0.f;
    #pragma unroll
    for (int k = 0; k < 6; ++k) {
      v[k] = sY[r][lane + k * 64];
      sum += v[k];
      sq = fmaf(v[k], v[k], sq);
    }
    #pragma unroll
    for (int off = 32; off >= 1; off >>= 1) {
      sum += __shfl_xor(sum, off, 64);
      sq  += __shfl_xor(sq,  off, 64);
    }
    const float mu = sum * (1.f / DI);
    const float var = sq * (1.f / DI) - mu * mu;
    const float rstd = rsqrtf(var + 1e-5f);
    #pragma unroll
    for (int k = 0; k < 6; ++k) {
      int dd = lane + k * 64;
      float t = (v[k] - mu) * rstd * ln_g[dd] + ln_b[dd];
      float z = xz[row * 768 + DI + dd];
      float outv = t * (z / (1.f + __expf(-z)));
      ushort hh16, ll16;
      split2(outv, hh16, ll16);
      ygh[row * DI + dd] = hh16;
      ygl[row * DI + dd] = ll16;
    }
  }
}

// ---------------------------------------------------------------------------
extern "C" void kernel_launch(void* const* d_in, const int* in_sizes, int n_in,
                              void* d_out, int out_size, void* d_ws, size_t ws_size,
                              hipStream_t stream) {
  const float* x             = (const float*)d_in[0];
  const float* prompt        = (const float*)d_in[1];
  const float* in_proj_w     = (const float*)d_in[2];
  const float* conv_w        = (const float*)d_in[3];
  const float* conv_b        = (const float*)d_in[4];
  const float* x_proj_w      = (const float*)d_in[5];
  const float* dt_proj_w     = (const float*)d_in[6];
  const float* dt_proj_b     = (const float*)d_in[7];
  const float* A_log         = (const float*)d_in[8];
  const float* Dp            = (const float*)d_in[9];
  const float* prompt_proj_w = (const float*)d_in[10];
  const float* ln_g          = (const float*)d_in[11];
  const float* ln_b          = (const float*)d_in[12];
  const float* out_proj_w    = (const float*)d_in[13];
  float* out = (float*)d_out;

  // workspace layout (bytes), total ~136 MB (ws is 256 MiB)
  char* p = (char*)d_ws;
  auto alloc = [&](size_t bytes) { char* r = p; p += (bytes + 255) & ~(size_t)255; return r; };
  float*  xz    = (float*)alloc((size_t)ML * 768 * 4);
  float*  xseq  = (float*)alloc((size_t)ML * DI * 4);
  float*  delta = (float*)alloc((size_t)ML * DI * 4);
  float*  xdbl  = (float*)alloc((size_t)ML * 64 * 4);
  float*  bv    = (float*)alloc((size_t)ML * NS * 4);
  float*  cv    = (float*)alloc((size_t)ML * NS * 4);
  float*  pb    = (float*)alloc((size_t)BB * NC * DI * NS * 4);
  float*  qb    = (float*)alloc((size_t)BB * NC * DI * NS * 4);
  float*  hin   = (float*)alloc((size_t)BB * NC * DI * NS * 4);
  ushort* w1h   = (ushort*)alloc((size_t)768 * DM * 2);
  ushort* w1l   = (ushort*)alloc((size_t)768 * DM * 2);
  ushort* w2h   = (ushort*)alloc((size_t)DM * DI * 2);
  ushort* w2l   = (ushort*)alloc((size_t)DM * DI * 2);
  ushort* wxh   = (ushort*)alloc((size_t)64 * DI * 2);
  ushort* wxl   = (ushort*)alloc((size_t)64 * DI * 2);
  ushort* xh    = (ushort*)alloc((size_t)ML * DM * 2);
  ushort* xl    = (ushort*)alloc((size_t)ML * DM * 2);
  ushort* xsh   = (ushort*)alloc((size_t)ML * DI * 2);
  ushort* xsl   = (ushort*)alloc((size_t)ML * DI * 2);
  ushort* ygh   = (ushort*)alloc((size_t)ML * DI * 2);
  ushort* ygl   = (ushort*)alloc((size_t)ML * DI * 2);
  float*  cwt   = (float*)alloc((size_t)9 * DI * 4);

  prep<<<1790, 256, 0, stream>>>(in_proj_w, out_proj_w, x_proj_w, x, conv_w,
                                 w1h, w1l, w2h, w2l, wxh, wxl, xh, xl, cwt);
  // in_proj: xz = x @ in_proj_w^T   (8192 x 768, K=192); 512 blocks
  gemm_sp<128, 96, 4, 3><<<dim3(8, 64), 256, 0, stream>>>(xh, xl, w1h, w1l, xz, ML, 768, DM);
  conv_silu<<<(ML * DI / 4) / 256, 256, 0, stream>>>(xz, cwt, conv_b, xseq, xsh, xsl);
  // x_dbl = x_seq @ x_proj_w^T (padded to 64 cols, K=384); 256 blocks
  gemm_sp<32, 64, 1, 2><<<dim3(1, 256), 256, 0, stream>>>(xsh, xsl, wxh, wxl, xdbl, ML, 64, DI);
  finish_kernel<<<ML / 16, 256, 0, stream>>>(xdbl, prompt, dt_proj_w, dt_proj_b,
                                             prompt_proj_w, delta, bv, cv);
  scan_pass1<<<BB * NC, DI, 0, stream>>>(delta, xseq, bv, A_log, pb, qb);
  scan_combine<<<(BB * DI * NS) / 256, 256, 0, stream>>>(pb, qb, hin);
  scan_pass2_ln<<<BB * NC, DI, 0, stream>>>(delta, xseq, bv, cv, A_log, Dp,
                                            hin, xz, ln_g, ln_b, ygh, ygl);
  // out = yg @ out_proj_w^T  (8192 x 192, K=384); 384 blocks
  gemm_sp<64, 64, 2, 2><<<dim3(3, 128), 256, 0, stream>>>(ygh, ygl, w2h, w2l, out, ML, DM, DI);
}

// Round 5
// 152.274 us; speedup vs baseline: 1.5004x; 1.0445x over previous
//
#include <hip/hip_runtime.h>
#include <hip/hip_bf16.h>
#include <math.h>

// Problem constants (fixed by the reference)
#define BB 2
#define HH 64
#define WW 64
#define DM 192            // d_model
#define DI 384            // d_inner
#define NS 16             // d_state
#define RK 12             // dt_rank
#define LL (HH*WW)        // 4096
#define ML (BB*LL)        // 8192 rows
#define NC 256            // scan chunks
#define CL 16             // chunk length; NC*CL == LL

typedef __attribute__((ext_vector_type(8))) short short8v;   // 8 bf16 (4 VGPRs)
typedef __attribute__((ext_vector_type(4))) float f32x4;

__device__ __forceinline__ ushort f2bf(float f) {
  unsigned u = __float_as_uint(f);
  u += 0x7fffu + ((u >> 16) & 1u);          // RNE
  return (ushort)(u >> 16);
}
__device__ __forceinline__ float bf2f(ushort h) {
  return __uint_as_float(((unsigned)h) << 16);
}
__device__ __forceinline__ void split2(float f, ushort& h, ushort& l) {
  h = f2bf(f);
  l = f2bf(f - bf2f(h));                    // residual; h+l ~ f to 2^-17 rel
}

// ---------------------------------------------------------------------------
// prep (vectorized x4): split f32 -> (bf16 hi, bf16 lo) for in_proj_w,
// out_proj_w, and x; tail transposes conv_w [384][9] -> conv_wt [9][384].
// ---------------------------------------------------------------------------
__global__ __launch_bounds__(256) void prep(
    const float* __restrict__ w1, const float* __restrict__ w2,
    const float* __restrict__ x, const float* __restrict__ conv_w,
    ushort* __restrict__ w1h, ushort* __restrict__ w1l,
    ushort* __restrict__ w2h, ushort* __restrict__ w2l,
    ushort* __restrict__ xh,  ushort* __restrict__ xl,
    float* __restrict__ conv_wt) {
  const int Q1 = 768 * DM / 4;       // 36864
  const int Q2 = DM * DI / 4;        // 18432
  const int Q4 = ML * DM / 4;        // 393216
  const int QT = Q1 + Q2 + Q4;       // 448512
  int i = blockIdx.x * 256 + threadIdx.x;
  if (i < QT) {
    const float* src; ushort* dh; ushort* dl; int j;
    if (i < Q1)           { src = w1; dh = w1h; dl = w1l; j = i; }
    else if (i < Q1 + Q2) { src = w2; dh = w2h; dl = w2l; j = i - Q1; }
    else                  { src = x;  dh = xh;  dl = xl;  j = i - Q1 - Q2; }
    float4 v = *reinterpret_cast<const float4*>(&src[(size_t)j * 4]);
    ushort4 h, l;
    split2(v.x, h.x, l.x); split2(v.y, h.y, l.y);
    split2(v.z, h.z, l.z); split2(v.w, h.w, l.w);
    *reinterpret_cast<ushort4*>(&dh[(size_t)j * 4]) = h;
    *reinterpret_cast<ushort4*>(&dl[(size_t)j * 4]) = l;
  } else if (i < QT + DI * 9) {
    int ct = i - QT;                 // over 3456
    int k = ct % 9, d = ct / 9;
    conv_wt[k * DI + d] = conv_w[ct];
  }
}

// ---------------------------------------------------------------------------
// Split-bf16 MFMA GEMM:  C[m,n] = sum_k A[m,k] * W[n,k]
// A, W both pre-split bf16 (hi, lo), row-major NxK.
// C = Ah*Wh + Ah*Wl + Al*Wh  (Al*Wl dropped, ~2^-16 relative)
// 4 waves in a 2x2 grid; wave tile (MR*16) x (NR*16); BM=2*MR*16, BN=2*NR*16.
// ---------------------------------------------------------------------------
template<int BM, int BN, int MR, int NR>
__global__ __launch_bounds__(256) void gemm_sp(
    const ushort* __restrict__ Ah, const ushort* __restrict__ Al,
    const ushort* __restrict__ Wh, const ushort* __restrict__ Wl,
    float* __restrict__ C, int M, int N, int K) {
  constexpr int RS = 40;                 // LDS row stride (bf16) = 32 + 8 pad
  __shared__ __align__(16) ushort sAh[BM * RS];
  __shared__ __align__(16) ushort sAl[BM * RS];
  __shared__ __align__(16) ushort sBh[BN * RS];
  __shared__ __align__(16) ushort sBl[BN * RS];
  const int tid = threadIdx.x;
  const int lane = tid & 63, wid = tid >> 6;
  const int wm = (wid >> 1) * (MR * 16);
  const int wn = (wid & 1) * (NR * 16);
  const int bm = blockIdx.y * BM;
  const int bn = blockIdx.x * BN;
  const int r16 = lane & 15;
  const int kb8 = (lane >> 4) * 8;

  f32x4 acc[MR][NR];
  #pragma unroll
  for (int m = 0; m < MR; ++m)
    #pragma unroll
    for (int n = 0; n < NR; ++n)
      acc[m][n] = (f32x4){0.f, 0.f, 0.f, 0.f};

  for (int k0 = 0; k0 < K; k0 += 32) {
    __syncthreads();   // WAR: previous iteration's fragment reads complete
    for (int i = tid; i < BM * 4; i += 256) {
      int row = i >> 2, kc = (i & 3) << 3;
      *reinterpret_cast<short8v*>(&sAh[row * RS + kc]) =
          *reinterpret_cast<const short8v*>(&Ah[(size_t)(bm + row) * K + k0 + kc]);
      *reinterpret_cast<short8v*>(&sAl[row * RS + kc]) =
          *reinterpret_cast<const short8v*>(&Al[(size_t)(bm + row) * K + k0 + kc]);
    }
    for (int i = tid; i < BN * 4; i += 256) {
      int row = i >> 2, kc = (i & 3) << 3;
      *reinterpret_cast<short8v*>(&sBh[row * RS + kc]) =
          *reinterpret_cast<const short8v*>(&Wh[(size_t)(bn + row) * K + k0 + kc]);
      *reinterpret_cast<short8v*>(&sBl[row * RS + kc]) =
          *reinterpret_cast<const short8v*>(&Wl[(size_t)(bn + row) * K + k0 + kc]);
    }
    __syncthreads();

    short8v ah[MR], al[MR], bh[NR], bl[NR];
    #pragma unroll
    for (int m = 0; m < MR; ++m) {
      int off = (wm + m * 16 + r16) * RS + kb8;
      ah[m] = *reinterpret_cast<const short8v*>(&sAh[off]);
      al[m] = *reinterpret_cast<const short8v*>(&sAl[off]);
    }
    #pragma unroll
    for (int n = 0; n < NR; ++n) {
      int off = (wn + n * 16 + r16) * RS + kb8;
      bh[n] = *reinterpret_cast<const short8v*>(&sBh[off]);
      bl[n] = *reinterpret_cast<const short8v*>(&sBl[off]);
    }
    #pragma unroll
    for (int m = 0; m < MR; ++m)
      #pragma unroll
      for (int n = 0; n < NR; ++n)
        acc[m][n] = __builtin_amdgcn_mfma_f32_16x16x32_bf16(ah[m], bh[n], acc[m][n], 0, 0, 0);
    #pragma unroll
    for (int m = 0; m < MR; ++m)
      #pragma unroll
      for (int n = 0; n < NR; ++n)
        acc[m][n] = __builtin_amdgcn_mfma_f32_16x16x32_bf16(ah[m], bl[n], acc[m][n], 0, 0, 0);
    #pragma unroll
    for (int m = 0; m < MR; ++m)
      #pragma unroll
      for (int n = 0; n < NR; ++n)
        acc[m][n] = __builtin_amdgcn_mfma_f32_16x16x32_bf16(al[m], bh[n], acc[m][n], 0, 0, 0);
  }

  const int cr = (lane >> 4) * 4;
  #pragma unroll
  for (int m = 0; m < MR; ++m)
    #pragma unroll
    for (int n = 0; n < NR; ++n) {
      int row = bm + wm + m * 16 + cr;
      int col = bn + wn + n * 16 + r16;
      #pragma unroll
      for (int r = 0; r < 4; ++r)
        C[(size_t)(row + r) * N + col] = acc[m][n][r];
    }
}

// ---------------------------------------------------------------------------
// Depthwise 3x3 conv (SAME) + bias + SiLU, vectorized x4 over d.
// ---------------------------------------------------------------------------
__global__ __launch_bounds__(256) void conv_silu(const float* __restrict__ xz,
                                                 const float* __restrict__ conv_wt,
                                                 const float* __restrict__ conv_b,
                                                 float* __restrict__ x_seq) {
  int t = blockIdx.x * 256 + threadIdx.x;      // over ML*DI/4
  int d4 = (t % (DI / 4)) * 4;
  int l  = (t / (DI / 4)) % LL;
  int b  = t / ((DI / 4) * LL);
  int h = l >> 6, w = l & 63;
  float4 acc = *reinterpret_cast<const float4*>(&conv_b[d4]);
  #pragma unroll
  for (int kh = 0; kh < 3; ++kh) {
    int hh = h + kh - 1;
    if (hh < 0 || hh >= HH) continue;
    #pragma unroll
    for (int kw = 0; kw < 3; ++kw) {
      int ww2 = w + kw - 1;
      if (ww2 < 0 || ww2 >= WW) continue;
      float4 v = *reinterpret_cast<const float4*>(
          &xz[((size_t)(b * LL + hh * WW + ww2)) * 768 + d4]);
      float4 wv = *reinterpret_cast<const float4*>(&conv_wt[(kh * 3 + kw) * DI + d4]);
      acc.x = fmaf(v.x, wv.x, acc.x); acc.y = fmaf(v.y, wv.y, acc.y);
      acc.z = fmaf(v.z, wv.z, acc.z); acc.w = fmaf(v.w, wv.w, acc.w);
    }
  }
  float4 sv;
  sv.x = acc.x / (1.f + __expf(-acc.x));
  sv.y = acc.y / (1.f + __expf(-acc.y));
  sv.z = acc.z / (1.f + __expf(-acc.z));
  sv.w = acc.w / (1.f + __expf(-acc.w));
  *reinterpret_cast<float4*>(&x_seq[(size_t)t * 4]) = sv;
}

// ---------------------------------------------------------------------------
// front_scan: fused {x_dbl projection (f32), dt_proj+softplus (double-bias,
// faithful), B/C (+prompt proj), scan pass 1} per (b, chunk) 16-row tile.
// 384 threads; ~72 KB LDS -> 2 blocks/CU.
// ---------------------------------------------------------------------------
__global__ __launch_bounds__(DI) void front_scan(
    const float* __restrict__ xseq,          // ML x DI
    const float* __restrict__ prompt,        // ML x DM
    const float* __restrict__ x_proj_w,      // 44 x DI
    const float* __restrict__ dt_proj_w,     // DI x RK
    const float* __restrict__ dt_proj_b,     // DI
    const float* __restrict__ prompt_proj_w, // NS x DM
    const float* __restrict__ A_log,         // DI x NS
    float* __restrict__ delta, float* __restrict__ Bv, float* __restrict__ Cv,
    float* __restrict__ Pb, float* __restrict__ Qb) {
  const int d = threadIdx.x;                 // 0..383
  const int c = blockIdx.x & (NC - 1);
  const int b = blockIdx.x >> 8;
  __shared__ float xs[CL][DI + 4];           // 16x388  (pad 4: 2-way max)
  __shared__ float pr[CL][DM + 4];           // 16x196
  __shared__ float pw[NS][DM + 4];           // 16x196
  __shared__ float sdt[RK][DI];              // 12x384 (dt_proj_w transposed)
  __shared__ float xd[CL][48];               // x_dbl tile (44 used)
  __shared__ float sB[CL][NS];
  const size_t row0 = (size_t)(b * LL + c * CL);

  for (int i = d; i < CL * 96; i += DI) {    // xs: 1536 float4
    int r = i / 96, c4 = (i % 96) * 4;
    *reinterpret_cast<float4*>(&xs[r][c4]) =
        *reinterpret_cast<const float4*>(&xseq[(row0 + r) * DI + c4]);
  }
  for (int i = d; i < CL * 48; i += DI) {    // pr: 768 float4
    int r = i / 48, c4 = (i % 48) * 4;
    *reinterpret_cast<float4*>(&pr[r][c4]) =
        *reinterpret_cast<const float4*>(&prompt[(row0 + r) * DM + c4]);
  }
  for (int i = d; i < NS * 48; i += DI) {    // pw: 768 float4
    int r = i / 48, c4 = (i % 48) * 4;
    *reinterpret_cast<float4*>(&pw[r][c4]) =
        *reinterpret_cast<const float4*>(&prompt_proj_w[r * DM + c4]);
  }
  for (int i = d; i < DI * RK; i += DI)      // sdt[j][dd] = dt_proj_w[dd][j]
    sdt[i % RK][i / RK] = dt_proj_w[i];
  __syncthreads();

  // x_dbl: 16 rows x 44 cols, f32 dot over DI from LDS; W from global (L2-hot)
  for (int o = d; o < CL * 44; o += DI) {
    int r = o & 15, j = o >> 4;              // 16-lane groups share j
    float acc = 0.f;
    for (int c4 = 0; c4 < DI; c4 += 4) {
      float4 xv = *reinterpret_cast<const float4*>(&xs[r][c4]);
      float4 wv = *reinterpret_cast<const float4*>(&x_proj_w[(size_t)j * DI + c4]);
      acc = fmaf(xv.x, wv.x, acc); acc = fmaf(xv.y, wv.y, acc);
      acc = fmaf(xv.z, wv.z, acc); acc = fmaf(xv.w, wv.w, acc);
    }
    xd[r][j] = acc;
  }
  __syncthreads();

  // delta for all 16 rows (regs + global), faithful double bias
  float sdtv[RK];
  #pragma unroll
  for (int j = 0; j < RK; ++j) sdtv[j] = sdt[j][d];
  const float db2 = 2.0f * dt_proj_b[d];
  float dlt[CL];
  #pragma unroll
  for (int r = 0; r < CL; ++r) {
    float acc = db2;
    #pragma unroll
    for (int j = 0; j < RK; ++j) acc = fmaf(xd[r][j], sdtv[j], acc);
    float sp = fmaxf(acc, 0.f) + log1pf(__expf(-fabsf(acc)));  // softplus
    dlt[r] = sp;
    delta[(row0 + r) * DI + d] = sp;
  }

  // B and C (256 threads; lanes n-fast)
  if (d < 256) {
    int r = d >> 4, n = d & 15;
    float bval = xd[r][12 + n];
    Bv[(row0 + r) * NS + n] = bval;
    sB[r][n] = bval;
    float acc = xd[r][28 + n];
    for (int c4 = 0; c4 < DM; c4 += 4) {
      float4 pv = *reinterpret_cast<const float4*>(&pr[r][c4]);
      float4 wv = *reinterpret_cast<const float4*>(&pw[n][c4]);
      acc = fmaf(pv.x, wv.x, acc); acc = fmaf(pv.y, wv.y, acc);
      acc = fmaf(pv.z, wv.z, acc); acc = fmaf(pv.w, wv.w, acc);
    }
    Cv[(row0 + r) * NS + n] = acc;
  }

  float a2[NS];
  #pragma unroll
  for (int n = 0; n < NS; n += 4) {
    float4 av = *reinterpret_cast<const float4*>(&A_log[d * NS + n]);
    a2[n+0] = -__expf(av.x) * 1.4426950408889634f;
    a2[n+1] = -__expf(av.y) * 1.4426950408889634f;
    a2[n+2] = -__expf(av.z) * 1.4426950408889634f;
    a2[n+3] = -__expf(av.w) * 1.4426950408889634f;
  }
  __syncthreads();                           // sB ready

  // scan pass 1 recurrence (inputs all in regs/LDS)
  float h[NS], p[NS];
  #pragma unroll
  for (int n = 0; n < NS; ++n) { h[n] = 0.f; p[n] = 1.f; }
  #pragma unroll
  for (int s = 0; s < CL; ++s) {
    float de = dlt[s];
    float du = de * xs[s][d];
    #pragma unroll
    for (int n = 0; n < NS; ++n) {
      float e = exp2f(de * a2[n]);
      h[n] = fmaf(e, h[n], du * sB[s][n]);
      p[n] *= e;
    }
  }
  const size_t base = ((size_t)(b * NC + c) * DI + d) * NS;
  #pragma unroll
  for (int n = 0; n < NS; n += 4) {
    *reinterpret_cast<float4*>(&Pb[base + n]) = make_float4(p[n], p[n+1], p[n+2], p[n+3]);
    *reinterpret_cast<float4*>(&Qb[base + n]) = make_float4(h[n], h[n+1], h[n+2], h[n+3]);
  }
}

// ---------------------------------------------------------------------------
// Segmented combine: block = 16 recurrences x 16 segments (16 chunks each).
// Phase A: per-thread segment aggregate (32 loads in flight, kept in regs).
// Phase B: tiny LDS scan over segments. Phase C: replay from registers.
// ---------------------------------------------------------------------------
__global__ __launch_bounds__(256) void scan_combine(const float* __restrict__ Pb,
                                                    const float* __restrict__ Qb,
                                                    float* __restrict__ Hout) {
  const int tid = threadIdx.x;
  const int dnl = tid & 15;                 // local recurrence
  const int seg = tid >> 4;                 // 0..15
  const int rec = blockIdx.x * 16 + dnl;    // 0..12287
  const int b = rec / (DI * NS);
  const int dn = rec % (DI * NS);
  const size_t S = DI * NS;
  const size_t base = (size_t)b * NC * S + dn;

  float p[16], q[16];
  #pragma unroll
  for (int i = 0; i < 16; ++i) {
    p[i] = Pb[base + (size_t)(seg * 16 + i) * S];
    q[i] = Qb[base + (size_t)(seg * 16 + i) * S];
  }
  float Pa = 1.f, Qa = 0.f;
  #pragma unroll
  for (int i = 0; i < 16; ++i) { Qa = fmaf(p[i], Qa, q[i]); Pa *= p[i]; }

  __shared__ float sP[16][17], sQ[16][17], sH[16][17];
  sP[dnl][seg] = Pa; sQ[dnl][seg] = Qa;
  __syncthreads();
  if (tid < 16) {                           // serial scan over 16 segments
    float hh = 0.f;
    #pragma unroll
    for (int s2 = 0; s2 < 16; ++s2) {
      sH[tid][s2] = hh;
      hh = fmaf(sP[tid][s2], hh, sQ[tid][s2]);
    }
  }
  __syncthreads();
  float h = sH[dnl][seg];
  #pragma unroll
  for (int i = 0; i < 16; ++i) {
    Hout[base + (size_t)(seg * 16 + i) * S] = h;
    h = fmaf(p[i], h, q[i]);
  }
}

// ---------------------------------------------------------------------------
// Pass 2 + fused LN + SiLU gate (round-4 structure, unchanged).
// ---------------------------------------------------------------------------
__global__ __launch_bounds__(DI) void scan_pass2_ln(
    const float* __restrict__ delta, const float* __restrict__ x_seq,
    const float* __restrict__ Bv, const float* __restrict__ Cv,
    const float* __restrict__ A_log, const float* __restrict__ Dp,
    const float* __restrict__ hin, const float* __restrict__ xz,
    const float* __restrict__ ln_g, const float* __restrict__ ln_b,
    ushort* __restrict__ ygh, ushort* __restrict__ ygl) {
  const int d = threadIdx.x;
  const int c = blockIdx.x & (NC - 1);
  const int b = blockIdx.x >> 8;
  __shared__ float sB[CL][NS], sC[CL][NS];
  __shared__ float sY[CL][DI + 1];
  for (int idx = threadIdx.x; idx < CL * NS; idx += DI) {
    size_t g = (size_t)(b * LL + c * CL) * NS + idx;
    sB[idx >> 4][idx & 15] = Bv[g];
    sC[idx >> 4][idx & 15] = Cv[g];
  }
  const size_t row0 = (size_t)(b * LL + c * CL);
  const size_t rowbase = row0 * DI + d;
  float dlt[CL], xu[CL];
  #pragma unroll
  for (int s = 0; s < CL; ++s) dlt[s] = delta[rowbase + (size_t)s * DI];
  #pragma unroll
  for (int s = 0; s < CL; ++s) xu[s]  = x_seq[rowbase + (size_t)s * DI];

  float a2[NS], h[NS];
  const size_t hbase = ((size_t)(b * NC + c) * DI + d) * NS;
  #pragma unroll
  for (int n = 0; n < NS; n += 4) {
    float4 hv = *reinterpret_cast<const float4*>(&hin[hbase + n]);
    h[n] = hv.x; h[n+1] = hv.y; h[n+2] = hv.z; h[n+3] = hv.w;
  }
  #pragma unroll
  for (int n = 0; n < NS; n += 4) {
    float4 av = *reinterpret_cast<const float4*>(&A_log[d * NS + n]);
    a2[n+0] = -__expf(av.x) * 1.4426950408889634f;
    a2[n+1] = -__expf(av.y) * 1.4426950408889634f;
    a2[n+2] = -__expf(av.z) * 1.4426950408889634f;
    a2[n+3] = -__expf(av.w) * 1.4426950408889634f;
  }
  const float Dd = Dp[d];
  __syncthreads();

  // phase 1: recurrence, no barriers
  #pragma unroll
  for (int s = 0; s < CL; ++s) {
    float de = dlt[s];
    float u  = xu[s];
    float du = de * u;
    float acc = Dd * u;
    #pragma unroll
    for (int n = 0; n < NS; ++n) {
      float e = exp2f(de * a2[n]);
      h[n] = fmaf(e, h[n], du * sB[s][n]);
      acc = fmaf(h[n], sC[s][n], acc);
    }
    sY[s][d] = acc;
  }
  __syncthreads();

  // phase 2: wave-per-row LayerNorm + gate + bf16 split
  const int wv = d >> 6, lane = d & 63;
  for (int r = wv; r < CL; r += 6) {
    const size_t row = row0 + r;
    float v[6];
    float sum = 0.f, sq = 0.f;
    #pragma unroll
    for (int k = 0; k < 6; ++k) {
      v[k] = sY[r][lane + k * 64];
      sum += v[k];
      sq = fmaf(v[k], v[k], sq);
    }
    #pragma unroll
    for (int off = 32; off >= 1; off >>= 1) {
      sum += __shfl_xor(sum, off, 64);
      sq  += __shfl_xor(sq,  off, 64);
    }
    const float mu = sum * (1.f / DI);
    const float var = sq * (1.f / DI) - mu * mu;
    const float rstd = rsqrtf(var + 1e-5f);
    #pragma unroll
    for (int k = 0; k < 6; ++k) {
      int dd = lane + k * 64;
      float t = (v[k] - mu) * rstd * ln_g[dd] + ln_b[dd];
      float z = xz[row * 768 + DI + dd];
      float outv = t * (z / (1.f + __expf(-z)));
      ushort hh16, ll16;
      split2(outv, hh16, ll16);
      ygh[row * DI + dd] = hh16;
      ygl[row * DI + dd] = ll16;
    }
  }
}

// ---------------------------------------------------------------------------
extern "C" void kernel_launch(void* const* d_in, const int* in_sizes, int n_in,
                              void* d_out, int out_size, void* d_ws, size_t ws_size,
                              hipStream_t stream) {
  const float* x             = (const float*)d_in[0];
  const float* prompt        = (const float*)d_in[1];
  const float* in_proj_w     = (const float*)d_in[2];
  const float* conv_w        = (const float*)d_in[3];
  const float* conv_b        = (const float*)d_in[4];
  const float* x_proj_w      = (const float*)d_in[5];
  const float* dt_proj_w     = (const float*)d_in[6];
  const float* dt_proj_b     = (const float*)d_in[7];
  const float* A_log         = (const float*)d_in[8];
  const float* Dp            = (const float*)d_in[9];
  const float* prompt_proj_w = (const float*)d_in[10];
  const float* ln_g          = (const float*)d_in[11];
  const float* ln_b          = (const float*)d_in[12];
  const float* out_proj_w    = (const float*)d_in[13];
  float* out = (float*)d_out;

  // workspace layout (bytes), total ~110 MB (ws is 256 MiB)
  char* p = (char*)d_ws;
  auto alloc = [&](size_t bytes) { char* r = p; p += (bytes + 255) & ~(size_t)255; return r; };
  float*  xz    = (float*)alloc((size_t)ML * 768 * 4);
  float*  xseq  = (float*)alloc((size_t)ML * DI * 4);
  float*  delta = (float*)alloc((size_t)ML * DI * 4);
  float*  bv    = (float*)alloc((size_t)ML * NS * 4);
  float*  cv    = (float*)alloc((size_t)ML * NS * 4);
  float*  pb    = (float*)alloc((size_t)BB * NC * DI * NS * 4);
  float*  qb    = (float*)alloc((size_t)BB * NC * DI * NS * 4);
  float*  hin   = (float*)alloc((size_t)BB * NC * DI * NS * 4);
  ushort* w1h   = (ushort*)alloc((size_t)768 * DM * 2);
  ushort* w1l   = (ushort*)alloc((size_t)768 * DM * 2);
  ushort* w2h   = (ushort*)alloc((size_t)DM * DI * 2);
  ushort* w2l   = (ushort*)alloc((size_t)DM * DI * 2);
  ushort* xh    = (ushort*)alloc((size_t)ML * DM * 2);
  ushort* xl    = (ushort*)alloc((size_t)ML * DM * 2);
  ushort* ygh   = (ushort*)alloc((size_t)ML * DI * 2);
  ushort* ygl   = (ushort*)alloc((size_t)ML * DI * 2);
  float*  cwt   = (float*)alloc((size_t)9 * DI * 4);

  prep<<<1766, 256, 0, stream>>>(in_proj_w, out_proj_w, x, conv_w,
                                 w1h, w1l, w2h, w2l, xh, xl, cwt);
  // in_proj: xz = x @ in_proj_w^T (8192 x 768, K=192); 1024 blocks = 4/CU
  gemm_sp<64, 96, 2, 3><<<dim3(8, 128), 256, 0, stream>>>(xh, xl, w1h, w1l, xz, ML, 768, DM);
  conv_silu<<<(ML * DI / 4) / 256, 256, 0, stream>>>(xz, cwt, conv_b, xseq);
  front_scan<<<BB * NC, DI, 0, stream>>>(xseq, prompt, x_proj_w, dt_proj_w,
                                         dt_proj_b, prompt_proj_w, A_log,
                                         delta, bv, cv, pb, qb);
  scan_combine<<<(BB * DI * NS) / 16, 256, 0, stream>>>(pb, qb, hin);
  scan_pass2_ln<<<BB * NC, DI, 0, stream>>>(delta, xseq, bv, cv, A_log, Dp,
                                            hin, xz, ln_g, ln_b, ygh, ygl);
  // out = yg @ out_proj_w^T (8192 x 192, K=384); 768 blocks = 3/CU
  gemm_sp<32, 64, 1, 2><<<dim3(3, 256), 256, 0, stream>>>(ygh, ygl, w2h, w2l, out, ML, DM, DI);
}

// Round 6
// 141.615 us; speedup vs baseline: 1.6133x; 1.0753x over previous
//
#include <hip/hip_runtime.h>
#include <hip/hip_bf16.h>
#include <math.h>

// Problem constants (fixed by the reference)
#define BB 2
#define HH 64
#define WW 64
#define DM 192            // d_model
#define DI 384            // d_inner
#define NS 16             // d_state
#define RK 12             // dt_rank
#define LL (HH*WW)        // 4096
#define ML (BB*LL)        // 8192 rows
#define NC 256            // scan chunks
#define CL 16             // chunk length; NC*CL == LL

typedef __attribute__((ext_vector_type(8))) short short8v;   // 8 bf16 (4 VGPRs)
typedef __attribute__((ext_vector_type(4))) float f32x4;

__device__ __forceinline__ ushort f2bf(float f) {
  unsigned u = __float_as_uint(f);
  u += 0x7fffu + ((u >> 16) & 1u);          // RNE
  return (ushort)(u >> 16);
}
__device__ __forceinline__ float bf2f(ushort h) {
  return __uint_as_float(((unsigned)h) << 16);
}
__device__ __forceinline__ void split2(float f, ushort& h, ushort& l) {
  h = f2bf(f);
  l = f2bf(f - bf2f(h));                    // residual; h+l ~ f to 2^-17 rel
}

// ---------------------------------------------------------------------------
// prep (vectorized x4): split f32 -> (bf16 hi, bf16 lo) for in_proj_w,
// out_proj_w, x_proj_w (zero-padded 44->64 rows), x; tail transposes
// conv_w [384][9] -> conv_wt [9][384].
// ---------------------------------------------------------------------------
__global__ __launch_bounds__(256) void prep(
    const float* __restrict__ w1, const float* __restrict__ w2,
    const float* __restrict__ wx, const float* __restrict__ x,
    const float* __restrict__ conv_w,
    ushort* __restrict__ w1h, ushort* __restrict__ w1l,
    ushort* __restrict__ w2h, ushort* __restrict__ w2l,
    ushort* __restrict__ wxh, ushort* __restrict__ wxl,
    ushort* __restrict__ xh,  ushort* __restrict__ xl,
    float* __restrict__ conv_wt) {
  const int Q1 = 768 * DM / 4;       // 36864
  const int Q2 = DM * DI / 4;        // 18432
  const int Q3 = 64 * DI / 4;        // 6144 (padded region)
  const int Q4 = ML * DM / 4;        // 393216
  const int QT = Q1 + Q2 + Q3 + Q4;  // 454656
  int i = blockIdx.x * 256 + threadIdx.x;
  if (i < QT) {
    const float* src; ushort* dh; ushort* dl; int j;
    if (i < Q1)                { src = w1; dh = w1h; dl = w1l; j = i; }
    else if (i < Q1 + Q2)      { src = w2; dh = w2h; dl = w2l; j = i - Q1; }
    else if (i < Q1 + Q2 + Q3) { src = wx; dh = wxh; dl = wxl; j = i - Q1 - Q2; }
    else                       { src = x;  dh = xh;  dl = xl;  j = i - Q1 - Q2 - Q3; }
    float4 v;
    if (dh == wxh && j * 4 >= 44 * DI) v = make_float4(0.f, 0.f, 0.f, 0.f);
    else v = *reinterpret_cast<const float4*>(&src[(size_t)j * 4]);
    ushort4 h, l;
    split2(v.x, h.x, l.x); split2(v.y, h.y, l.y);
    split2(v.z, h.z, l.z); split2(v.w, h.w, l.w);
    *reinterpret_cast<ushort4*>(&dh[(size_t)j * 4]) = h;
    *reinterpret_cast<ushort4*>(&dl[(size_t)j * 4]) = l;
  } else if (i < QT + DI * 9) {
    int ct = i - QT;                 // over 3456
    int k = ct % 9, d = ct / 9;
    conv_wt[k * DI + d] = conv_w[ct];
  }
}

// ---------------------------------------------------------------------------
// Split-bf16 MFMA GEMM:  C[m,n] = sum_k A[m,k] * W[n,k]
// A, W both pre-split bf16 (hi, lo), row-major NxK.
// C = Ah*Wh + Ah*Wl + Al*Wh  (Al*Wl dropped, ~2^-16 relative)
// 4 waves in a 2x2 grid; wave tile (MR*16) x (NR*16); BM=2*MR*16, BN=2*NR*16.
// ---------------------------------------------------------------------------
template<int BM, int BN, int MR, int NR>
__global__ __launch_bounds__(256) void gemm_sp(
    const ushort* __restrict__ Ah, const ushort* __restrict__ Al,
    const ushort* __restrict__ Wh, const ushort* __restrict__ Wl,
    float* __restrict__ C, int M, int N, int K) {
  constexpr int RS = 40;                 // LDS row stride (bf16) = 32 + 8 pad
  __shared__ __align__(16) ushort sAh[BM * RS];
  __shared__ __align__(16) ushort sAl[BM * RS];
  __shared__ __align__(16) ushort sBh[BN * RS];
  __shared__ __align__(16) ushort sBl[BN * RS];
  const int tid = threadIdx.x;
  const int lane = tid & 63, wid = tid >> 6;
  const int wm = (wid >> 1) * (MR * 16);
  const int wn = (wid & 1) * (NR * 16);
  const int bm = blockIdx.y * BM;
  const int bn = blockIdx.x * BN;
  const int r16 = lane & 15;
  const int kb8 = (lane >> 4) * 8;

  f32x4 acc[MR][NR];
  #pragma unroll
  for (int m = 0; m < MR; ++m)
    #pragma unroll
    for (int n = 0; n < NR; ++n)
      acc[m][n] = (f32x4){0.f, 0.f, 0.f, 0.f};

  for (int k0 = 0; k0 < K; k0 += 32) {
    __syncthreads();   // WAR: previous iteration's fragment reads complete
    for (int i = tid; i < BM * 4; i += 256) {
      int row = i >> 2, kc = (i & 3) << 3;
      *reinterpret_cast<short8v*>(&sAh[row * RS + kc]) =
          *reinterpret_cast<const short8v*>(&Ah[(size_t)(bm + row) * K + k0 + kc]);
      *reinterpret_cast<short8v*>(&sAl[row * RS + kc]) =
          *reinterpret_cast<const short8v*>(&Al[(size_t)(bm + row) * K + k0 + kc]);
    }
    for (int i = tid; i < BN * 4; i += 256) {
      int row = i >> 2, kc = (i & 3) << 3;
      *reinterpret_cast<short8v*>(&sBh[row * RS + kc]) =
          *reinterpret_cast<const short8v*>(&Wh[(size_t)(bn + row) * K + k0 + kc]);
      *reinterpret_cast<short8v*>(&sBl[row * RS + kc]) =
          *reinterpret_cast<const short8v*>(&Wl[(size_t)(bn + row) * K + k0 + kc]);
    }
    __syncthreads();

    short8v ah[MR], al[MR], bh[NR], bl[NR];
    #pragma unroll
    for (int m = 0; m < MR; ++m) {
      int off = (wm + m * 16 + r16) * RS + kb8;
      ah[m] = *reinterpret_cast<const short8v*>(&sAh[off]);
      al[m] = *reinterpret_cast<const short8v*>(&sAl[off]);
    }
    #pragma unroll
    for (int n = 0; n < NR; ++n) {
      int off = (wn + n * 16 + r16) * RS + kb8;
      bh[n] = *reinterpret_cast<const short8v*>(&sBh[off]);
      bl[n] = *reinterpret_cast<const short8v*>(&sBl[off]);
    }
    #pragma unroll
    for (int m = 0; m < MR; ++m)
      #pragma unroll
      for (int n = 0; n < NR; ++n)
        acc[m][n] = __builtin_amdgcn_mfma_f32_16x16x32_bf16(ah[m], bh[n], acc[m][n], 0, 0, 0);
    #pragma unroll
    for (int m = 0; m < MR; ++m)
      #pragma unroll
      for (int n = 0; n < NR; ++n)
        acc[m][n] = __builtin_amdgcn_mfma_f32_16x16x32_bf16(ah[m], bl[n], acc[m][n], 0, 0, 0);
    #pragma unroll
    for (int m = 0; m < MR; ++m)
      #pragma unroll
      for (int n = 0; n < NR; ++n)
        acc[m][n] = __builtin_amdgcn_mfma_f32_16x16x32_bf16(al[m], bh[n], acc[m][n], 0, 0, 0);
  }

  const int cr = (lane >> 4) * 4;
  #pragma unroll
  for (int m = 0; m < MR; ++m)
    #pragma unroll
    for (int n = 0; n < NR; ++n) {
      int row = bm + wm + m * 16 + cr;
      int col = bn + wn + n * 16 + r16;
      #pragma unroll
      for (int r = 0; r < 4; ++r)
        C[(size_t)(row + r) * N + col] = acc[m][n][r];
    }
}

// ---------------------------------------------------------------------------
// Depthwise 3x3 conv (SAME) + bias + SiLU, vectorized x4 over d.
// Emits f32 (for the scan) and bf16 hi/lo (for the x_dbl GEMM).
// ---------------------------------------------------------------------------
__global__ __launch_bounds__(256) void conv_silu(const float* __restrict__ xz,
                                                 const float* __restrict__ conv_wt,
                                                 const float* __restrict__ conv_b,
                                                 float* __restrict__ x_seq,
                                                 ushort* __restrict__ xsh,
                                                 ushort* __restrict__ xsl) {
  int t = blockIdx.x * 256 + threadIdx.x;      // over ML*DI/4
  int d4 = (t % (DI / 4)) * 4;
  int l  = (t / (DI / 4)) % LL;
  int b  = t / ((DI / 4) * LL);
  int h = l >> 6, w = l & 63;
  float4 acc = *reinterpret_cast<const float4*>(&conv_b[d4]);
  #pragma unroll
  for (int kh = 0; kh < 3; ++kh) {
    int hh = h + kh - 1;
    if (hh < 0 || hh >= HH) continue;
    #pragma unroll
    for (int kw = 0; kw < 3; ++kw) {
      int ww2 = w + kw - 1;
      if (ww2 < 0 || ww2 >= WW) continue;
      float4 v = *reinterpret_cast<const float4*>(
          &xz[((size_t)(b * LL + hh * WW + ww2)) * 768 + d4]);
      float4 wv = *reinterpret_cast<const float4*>(&conv_wt[(kh * 3 + kw) * DI + d4]);
      acc.x = fmaf(v.x, wv.x, acc.x); acc.y = fmaf(v.y, wv.y, acc.y);
      acc.z = fmaf(v.z, wv.z, acc.z); acc.w = fmaf(v.w, wv.w, acc.w);
    }
  }
  float4 sv;
  sv.x = acc.x / (1.f + __expf(-acc.x));
  sv.y = acc.y / (1.f + __expf(-acc.y));
  sv.z = acc.z / (1.f + __expf(-acc.z));
  sv.w = acc.w / (1.f + __expf(-acc.w));
  size_t o = (size_t)t * 4;
  *reinterpret_cast<float4*>(&x_seq[o]) = sv;
  ushort4 hh4, ll4;
  split2(sv.x, hh4.x, ll4.x); split2(sv.y, hh4.y, ll4.y);
  split2(sv.z, hh4.z, ll4.z); split2(sv.w, hh4.w, ll4.w);
  *reinterpret_cast<ushort4*>(&xsh[o]) = hh4;
  *reinterpret_cast<ushort4*>(&xsl[o]) = ll4;
}

// ---------------------------------------------------------------------------
// mid_scan: fused finish + scan pass 1 per (b, chunk) = 16-row tile.
// 384 threads, ~29 KB LDS. From xdbl (GEMM output): delta = softplus(
// xdbl[:12] @ dt_w^T + 2*dt_b) (faithful double-bias, dt_w register-resident),
// B = xdbl[12:28], C = xdbl[28:44] + prompt @ pw^T, then the pass-1
// recurrence with delta in registers. No serial long dots (round-5 lesson).
// ---------------------------------------------------------------------------
__global__ __launch_bounds__(DI) void mid_scan(
    const float* __restrict__ xdbl,          // ML x 64
    const float* __restrict__ prompt,        // ML x DM
    const float* __restrict__ xseq,          // ML x DI
    const float* __restrict__ dt_proj_w,     // DI x RK (row-contiguous per d)
    const float* __restrict__ dt_proj_b,     // DI
    const float* __restrict__ prompt_proj_w, // NS x DM
    const float* __restrict__ A_log,         // DI x NS
    float* __restrict__ delta, float* __restrict__ Bv, float* __restrict__ Cv,
    float* __restrict__ Pb, float* __restrict__ Qb) {
  const int d = threadIdx.x;                 // 0..383
  const int c = blockIdx.x & (NC - 1);
  const int b = blockIdx.x >> 8;
  __shared__ float xd[CL][48];               // x_dbl tile (44 used)
  __shared__ float pr[CL][DM + 4];
  __shared__ float pw[NS][DM + 4];
  __shared__ float sB[CL][NS];
  const size_t row0 = (size_t)(b * LL + c * CL);

  for (int i = d; i < CL * 12; i += DI) {    // xd: 192 float4
    int r = i / 12, c4 = (i % 12) * 4;
    *reinterpret_cast<float4*>(&xd[r][c4]) =
        *reinterpret_cast<const float4*>(&xdbl[(row0 + r) * 64 + c4]);
  }
  for (int i = d; i < CL * 48; i += DI) {    // pr: 768 float4
    int r = i / 48, c4 = (i % 48) * 4;
    *reinterpret_cast<float4*>(&pr[r][c4]) =
        *reinterpret_cast<const float4*>(&prompt[(row0 + r) * DM + c4]);
  }
  for (int i = d; i < NS * 48; i += DI) {    // pw: 768 float4
    int r = i / 48, c4 = (i % 48) * 4;
    *reinterpret_cast<float4*>(&pw[r][c4]) =
        *reinterpret_cast<const float4*>(&prompt_proj_w[r * DM + c4]);
  }

  // register-resident per-thread params (independent loads, off any chain)
  float sdtv[RK];                            // dt_proj_w row d (contiguous)
  #pragma unroll
  for (int j = 0; j < RK; j += 4) {
    float4 v = *reinterpret_cast<const float4*>(&dt_proj_w[(size_t)d * RK + j]);
    sdtv[j] = v.x; sdtv[j+1] = v.y; sdtv[j+2] = v.z; sdtv[j+3] = v.w;
  }
  const float db2 = 2.0f * dt_proj_b[d];     // bias applied twice (faithful)
  float a2[NS];
  #pragma unroll
  for (int n = 0; n < NS; n += 4) {
    float4 av = *reinterpret_cast<const float4*>(&A_log[d * NS + n]);
    a2[n+0] = -__expf(av.x) * 1.4426950408889634f;
    a2[n+1] = -__expf(av.y) * 1.4426950408889634f;
    a2[n+2] = -__expf(av.z) * 1.4426950408889634f;
    a2[n+3] = -__expf(av.w) * 1.4426950408889634f;
  }
  const size_t rowbase = row0 * DI + d;
  float xu[CL];
  #pragma unroll
  for (int s = 0; s < CL; ++s) xu[s] = xseq[rowbase + (size_t)s * DI];
  __syncthreads();                           // xd/pr/pw staged

  // delta for all 16 rows (RK=12 dot from LDS + regs)
  float dlt[CL];
  #pragma unroll
  for (int r = 0; r < CL; ++r) {
    float acc = db2;
    #pragma unroll
    for (int j = 0; j < RK; ++j) acc = fmaf(xd[r][j], sdtv[j], acc);
    float sp = fmaxf(acc, 0.f) + log1pf(__expf(-fabsf(acc)));  // softplus
    dlt[r] = sp;
    delta[(row0 + r) * DI + d] = sp;
  }

  // B and C (256 threads; lanes n-fast for coalesced writes)
  if (d < 256) {
    int r = d >> 4, n = d & 15;
    float bval = xd[r][12 + n];
    Bv[(row0 + r) * NS + n] = bval;
    sB[r][n] = bval;
    float acc = xd[r][28 + n];
    for (int c4 = 0; c4 < DM; c4 += 4) {
      float4 pv = *reinterpret_cast<const float4*>(&pr[r][c4]);
      float4 wv = *reinterpret_cast<const float4*>(&pw[n][c4]);
      acc = fmaf(pv.x, wv.x, acc); acc = fmaf(pv.y, wv.y, acc);
      acc = fmaf(pv.z, wv.z, acc); acc = fmaf(pv.w, wv.w, acc);
    }
    Cv[(row0 + r) * NS + n] = acc;
  }
  __syncthreads();                           // sB ready

  // scan pass 1 recurrence (all inputs in regs/LDS)
  float h[NS], p[NS];
  #pragma unroll
  for (int n = 0; n < NS; ++n) { h[n] = 0.f; p[n] = 1.f; }
  #pragma unroll
  for (int s = 0; s < CL; ++s) {
    float de = dlt[s];
    float du = de * xu[s];
    #pragma unroll
    for (int n = 0; n < NS; ++n) {
      float e = exp2f(de * a2[n]);
      h[n] = fmaf(e, h[n], du * sB[s][n]);
      p[n] *= e;
    }
  }
  const size_t base = ((size_t)(b * NC + c) * DI + d) * NS;
  #pragma unroll
  for (int n = 0; n < NS; n += 4) {
    *reinterpret_cast<float4*>(&Pb[base + n]) = make_float4(p[n], p[n+1], p[n+2], p[n+3]);
    *reinterpret_cast<float4*>(&Qb[base + n]) = make_float4(h[n], h[n+1], h[n+2], h[n+3]);
  }
}

// ---------------------------------------------------------------------------
// Segmented combine: block = 16 recurrences x 16 segments (16 chunks each).
// ---------------------------------------------------------------------------
__global__ __launch_bounds__(256) void scan_combine(const float* __restrict__ Pb,
                                                    const float* __restrict__ Qb,
                                                    float* __restrict__ Hout) {
  const int tid = threadIdx.x;
  const int dnl = tid & 15;                 // local recurrence
  const int seg = tid >> 4;                 // 0..15
  const int rec = blockIdx.x * 16 + dnl;    // 0..12287
  const int b = rec / (DI * NS);
  const int dn = rec % (DI * NS);
  const size_t S = DI * NS;
  const size_t base = (size_t)b * NC * S + dn;

  float p[16], q[16];
  #pragma unroll
  for (int i = 0; i < 16; ++i) {
    p[i] = Pb[base + (size_t)(seg * 16 + i) * S];
    q[i] = Qb[base + (size_t)(seg * 16 + i) * S];
  }
  float Pa = 1.f, Qa = 0.f;
  #pragma unroll
  for (int i = 0; i < 16; ++i) { Qa = fmaf(p[i], Qa, q[i]); Pa *= p[i]; }

  __shared__ float sP[16][17], sQ[16][17], sH[16][17];
  sP[dnl][seg] = Pa; sQ[dnl][seg] = Qa;
  __syncthreads();
  if (tid < 16) {                           // serial scan over 16 segments
    float hh = 0.f;
    #pragma unroll
    for (int s2 = 0; s2 < 16; ++s2) {
      sH[tid][s2] = hh;
      hh = fmaf(sP[tid][s2], hh, sQ[tid][s2]);
    }
  }
  __syncthreads();
  float h = sH[dnl][seg];
  #pragma unroll
  for (int i = 0; i < 16; ++i) {
    Hout[base + (size_t)(seg * 16 + i) * S] = h;
    h = fmaf(p[i], h, q[i]);
  }
}

// ---------------------------------------------------------------------------
// Pass 2 + fused LN + SiLU gate (proven round-4/5 structure).
// ---------------------------------------------------------------------------
__global__ __launch_bounds__(DI) void scan_pass2_ln(
    const float* __restrict__ delta, const float* __restrict__ x_seq,
    const float* __restrict__ Bv, const float* __restrict__ Cv,
    const float* __restrict__ A_log, const float* __restrict__ Dp,
    const float* __restrict__ hin, const float* __restrict__ xz,
    const float* __restrict__ ln_g, const float* __restrict__ ln_b,
    ushort* __restrict__ ygh, ushort* __restrict__ ygl) {
  const int d = threadIdx.x;
  const int c = blockIdx.x & (NC - 1);
  const int b = blockIdx.x >> 8;
  __shared__ float sB[CL][NS], sC[CL][NS];
  __shared__ float sY[CL][DI + 1];
  for (int idx = threadIdx.x; idx < CL * NS; idx += DI) {
    size_t g = (size_t)(b * LL + c * CL) * NS + idx;
    sB[idx >> 4][idx & 15] = Bv[g];
    sC[idx >> 4][idx & 15] = Cv[g];
  }
  const size_t row0 = (size_t)(b * LL + c * CL);
  const size_t rowbase = row0 * DI + d;
  float dlt[CL], xu[CL];
  #pragma unroll
  for (int s = 0; s < CL; ++s) dlt[s] = delta[rowbase + (size_t)s * DI];
  #pragma unroll
  for (int s = 0; s < CL; ++s) xu[s]  = x_seq[rowbase + (size_t)s * DI];

  float a2[NS], h[NS];
  const size_t hbase = ((size_t)(b * NC + c) * DI + d) * NS;
  #pragma unroll
  for (int n = 0; n < NS; n += 4) {
    float4 hv = *reinterpret_cast<const float4*>(&hin[hbase + n]);
    h[n] = hv.x; h[n+1] = hv.y; h[n+2] = hv.z; h[n+3] = hv.w;
  }
  #pragma unroll
  for (int n = 0; n < NS; n += 4) {
    float4 av = *reinterpret_cast<const float4*>(&A_log[d * NS + n]);
    a2[n+0] = -__expf(av.x) * 1.4426950408889634f;
    a2[n+1] = -__expf(av.y) * 1.4426950408889634f;
    a2[n+2] = -__expf(av.z) * 1.4426950408889634f;
    a2[n+3] = -__expf(av.w) * 1.4426950408889634f;
  }
  const float Dd = Dp[d];
  __syncthreads();

  // phase 1: recurrence, no barriers
  #pragma unroll
  for (int s = 0; s < CL; ++s) {
    float de = dlt[s];
    float u  = xu[s];
    float du = de * u;
    float acc = Dd * u;
    #pragma unroll
    for (int n = 0; n < NS; ++n) {
      float e = exp2f(de * a2[n]);
      h[n] = fmaf(e, h[n], du * sB[s][n]);
      acc = fmaf(h[n], sC[s][n], acc);
    }
    sY[s][d] = acc;
  }
  __syncthreads();

  // phase 2: wave-per-row LayerNorm + gate + bf16 split
  const int wv = d >> 6, lane = d & 63;
  for (int r = wv; r < CL; r += 6) {
    const size_t row = row0 + r;
    float v[6];
    float sum = 0.f, sq = 0.f;
    #pragma unroll
    for (int k = 0; k < 6; ++k) {
      v[k] = sY[r][lane + k * 64];
      sum += v[k];
      sq = fmaf(v[k], v[k], sq);
    }
    #pragma unroll
    for (int off = 32; off >= 1; off >>= 1) {
      sum += __shfl_xor(sum, off, 64);
      sq  += __shfl_xor(sq,  off, 64);
    }
    const float mu = sum * (1.f / DI);
    const float var = sq * (1.f / DI) - mu * mu;
    const float rstd = rsqrtf(var + 1e-5f);
    #pragma unroll
    for (int k = 0; k < 6; ++k) {
      int dd = lane + k * 64;
      float t = (v[k] - mu) * rstd * ln_g[dd] + ln_b[dd];
      float z = xz[row * 768 + DI + dd];
      float outv = t * (z / (1.f + __expf(-z)));
      ushort hh16, ll16;
      split2(outv, hh16, ll16);
      ygh[row * DI + dd] = hh16;
      ygl[row * DI + dd] = ll16;
    }
  }
}

// ---------------------------------------------------------------------------
extern "C" void kernel_launch(void* const* d_in, const int* in_sizes, int n_in,
                              void* d_out, int out_size, void* d_ws, size_t ws_size,
                              hipStream_t stream) {
  const float* x             = (const float*)d_in[0];
  const float* prompt        = (const float*)d_in[1];
  const float* in_proj_w     = (const float*)d_in[2];
  const float* conv_w        = (const float*)d_in[3];
  const float* conv_b        = (const float*)d_in[4];
  const float* x_proj_w      = (const float*)d_in[5];
  const float* dt_proj_w     = (const float*)d_in[6];
  const float* dt_proj_b     = (const float*)d_in[7];
  const float* A_log         = (const float*)d_in[8];
  const float* Dp            = (const float*)d_in[9];
  const float* prompt_proj_w = (const float*)d_in[10];
  const float* ln_g          = (const float*)d_in[11];
  const float* ln_b          = (const float*)d_in[12];
  const float* out_proj_w    = (const float*)d_in[13];
  float* out = (float*)d_out;

  // workspace layout (bytes), total ~137 MB (ws is 256 MiB)
  char* p = (char*)d_ws;
  auto alloc = [&](size_t bytes) { char* r = p; p += (bytes + 255) & ~(size_t)255; return r; };
  float*  xz    = (float*)alloc((size_t)ML * 768 * 4);
  float*  xseq  = (float*)alloc((size_t)ML * DI * 4);
  float*  delta = (float*)alloc((size_t)ML * DI * 4);
  float*  xdbl  = (float*)alloc((size_t)ML * 64 * 4);
  float*  bv    = (float*)alloc((size_t)ML * NS * 4);
  float*  cv    = (float*)alloc((size_t)ML * NS * 4);
  float*  pb    = (float*)alloc((size_t)BB * NC * DI * NS * 4);
  float*  qb    = (float*)alloc((size_t)BB * NC * DI * NS * 4);
  float*  hin   = (float*)alloc((size_t)BB * NC * DI * NS * 4);
  ushort* w1h   = (ushort*)alloc((size_t)768 * DM * 2);
  ushort* w1l   = (ushort*)alloc((size_t)768 * DM * 2);
  ushort* w2h   = (ushort*)alloc((size_t)DM * DI * 2);
  ushort* w2l   = (ushort*)alloc((size_t)DM * DI * 2);
  ushort* wxh   = (ushort*)alloc((size_t)64 * DI * 2);
  ushort* wxl   = (ushort*)alloc((size_t)64 * DI * 2);
  ushort* xh    = (ushort*)alloc((size_t)ML * DM * 2);
  ushort* xl    = (ushort*)alloc((size_t)ML * DM * 2);
  ushort* xsh   = (ushort*)alloc((size_t)ML * DI * 2);
  ushort* xsl   = (ushort*)alloc((size_t)ML * DI * 2);
  ushort* ygh   = (ushort*)alloc((size_t)ML * DI * 2);
  ushort* ygl   = (ushort*)alloc((size_t)ML * DI * 2);
  float*  cwt   = (float*)alloc((size_t)9 * DI * 4);

  prep<<<1790, 256, 0, stream>>>(in_proj_w, out_proj_w, x_proj_w, x, conv_w,
                                 w1h, w1l, w2h, w2l, wxh, wxl, xh, xl, cwt);
  // in_proj: xz = x @ in_proj_w^T (8192 x 768, K=192); 1024 blocks = 4/CU
  gemm_sp<64, 96, 2, 3><<<dim3(8, 128), 256, 0, stream>>>(xh, xl, w1h, w1l, xz, ML, 768, DM);
  conv_silu<<<(ML * DI / 4) / 256, 256, 0, stream>>>(xz, cwt, conv_b, xseq, xsh, xsl);
  // x_dbl = x_seq @ x_proj_w^T (padded to 64 cols, K=384); 256 blocks
  gemm_sp<32, 64, 1, 2><<<dim3(1, 256), 256, 0, stream>>>(xsh, xsl, wxh, wxl, xdbl, ML, 64, DI);
  mid_scan<<<BB * NC, DI, 0, stream>>>(xdbl, prompt, xseq, dt_proj_w, dt_proj_b,
                                       prompt_proj_w, A_log, delta, bv, cv, pb, qb);
  scan_combine<<<(BB * DI * NS) / 16, 256, 0, stream>>>(pb, qb, hin);
  scan_pass2_ln<<<BB * NC, DI, 0, stream>>>(delta, xseq, bv, cv, A_log, Dp,
                                            hin, xz, ln_g, ln_b, ygh, ygl);
  // out = yg @ out_proj_w^T (8192 x 192, K=384); 768 blocks = 3/CU
  gemm_sp<32, 64, 1, 2><<<dim3(3, 256), 256, 0, stream>>>(ygh, ygl, w2h, w2l, out, ML, DM, DI);
}

// Round 8
// 124.899 us; speedup vs baseline: 1.8292x; 1.1338x over previous
//
#include <hip/hip_runtime.h>
#include <hip/hip_bf16.h>
#include <math.h>

// Problem constants (fixed by the reference)
#define BB 2
#define HH 64
#define WW 64
#define DM 192            // d_model
#define DI 384            // d_inner
#define NS 16             // d_state
#define RK 12             // dt_rank
#define LL (HH*WW)        // 4096
#define ML (BB*LL)        // 8192 rows
#define NC 256            // scan chunks
#define CL 16             // chunk length; NC*CL == LL

typedef __attribute__((ext_vector_type(8))) short short8v;   // 8 bf16 (4 VGPRs)
typedef __attribute__((ext_vector_type(4))) float f32x4;

__device__ __forceinline__ ushort f2bf(float f) {
  unsigned u = __float_as_uint(f);
  u += 0x7fffu + ((u >> 16) & 1u);          // RNE
  return (ushort)(u >> 16);
}
__device__ __forceinline__ float bf2f(ushort h) {
  return __uint_as_float(((unsigned)h) << 16);
}
__device__ __forceinline__ void split2(float f, ushort& h, ushort& l) {
  h = f2bf(f);
  l = f2bf(f - bf2f(h));                    // residual; h+l ~ f to 2^-17 rel
}
// fast softplus: max(x,0) + log(1 + exp(-|x|)) with native exp/log
__device__ __forceinline__ float softplus_fast(float x) {
  float e = __expf(-fabsf(x));
  return fmaxf(x, 0.f) + __logf(1.f + e);
}

// ---------------------------------------------------------------------------
// prep (vectorized x4): split f32 -> (bf16 hi, bf16 lo) for in_proj_w,
// out_proj_w, x_proj_w (zero-padded 44->64 rows), x; tail transposes
// conv_w [384][9] -> conv_wt [9][384].
// ---------------------------------------------------------------------------
__global__ __launch_bounds__(256) void prep(
    const float* __restrict__ w1, const float* __restrict__ w2,
    const float* __restrict__ wx, const float* __restrict__ x,
    const float* __restrict__ conv_w,
    ushort* __restrict__ w1h, ushort* __restrict__ w1l,
    ushort* __restrict__ w2h, ushort* __restrict__ w2l,
    ushort* __restrict__ wxh, ushort* __restrict__ wxl,
    ushort* __restrict__ xh,  ushort* __restrict__ xl,
    float* __restrict__ conv_wt) {
  const int Q1 = 768 * DM / 4;       // 36864
  const int Q2 = DM * DI / 4;        // 18432
  const int Q3 = 64 * DI / 4;        // 6144 (padded region)
  const int Q4 = ML * DM / 4;        // 393216
  const int QT = Q1 + Q2 + Q3 + Q4;  // 454656
  int i = blockIdx.x * 256 + threadIdx.x;
  if (i < QT) {
    const float* src; ushort* dh; ushort* dl; int j;
    if (i < Q1)                { src = w1; dh = w1h; dl = w1l; j = i; }
    else if (i < Q1 + Q2)      { src = w2; dh = w2h; dl = w2l; j = i - Q1; }
    else if (i < Q1 + Q2 + Q3) { src = wx; dh = wxh; dl = wxl; j = i - Q1 - Q2; }
    else                       { src = x;  dh = xh;  dl = xl;  j = i - Q1 - Q2 - Q3; }
    float4 v;
    if (dh == wxh && j * 4 >= 44 * DI) v = make_float4(0.f, 0.f, 0.f, 0.f);
    else v = *reinterpret_cast<const float4*>(&src[(size_t)j * 4]);
    ushort4 h, l;
    split2(v.x, h.x, l.x); split2(v.y, h.y, l.y);
    split2(v.z, h.z, l.z); split2(v.w, h.w, l.w);
    *reinterpret_cast<ushort4*>(&dh[(size_t)j * 4]) = h;
    *reinterpret_cast<ushort4*>(&dl[(size_t)j * 4]) = l;
  } else if (i < QT + DI * 9) {
    int ct = i - QT;                 // over 3456
    int k = ct % 9, d = ct / 9;
    conv_wt[k * DI + d] = conv_w[ct];
  }
}

// ---------------------------------------------------------------------------
// Split-bf16 MFMA GEMM:  C[m,n] = sum_k A[m,k] * W[n,k]
// ---------------------------------------------------------------------------
template<int BM, int BN, int MR, int NR>
__global__ __launch_bounds__(256) void gemm_sp(
    const ushort* __restrict__ Ah, const ushort* __restrict__ Al,
    const ushort* __restrict__ Wh, const ushort* __restrict__ Wl,
    float* __restrict__ C, int M, int N, int K) {
  constexpr int RS = 40;                 // LDS row stride (bf16) = 32 + 8 pad
  __shared__ __align__(16) ushort sAh[BM * RS];
  __shared__ __align__(16) ushort sAl[BM * RS];
  __shared__ __align__(16) ushort sBh[BN * RS];
  __shared__ __align__(16) ushort sBl[BN * RS];
  const int tid = threadIdx.x;
  const int lane = tid & 63, wid = tid >> 6;
  const int wm = (wid >> 1) * (MR * 16);
  const int wn = (wid & 1) * (NR * 16);
  const int bm = blockIdx.y * BM;
  const int bn = blockIdx.x * BN;
  const int r16 = lane & 15;
  const int kb8 = (lane >> 4) * 8;

  f32x4 acc[MR][NR];
  #pragma unroll
  for (int m = 0; m < MR; ++m)
    #pragma unroll
    for (int n = 0; n < NR; ++n)
      acc[m][n] = (f32x4){0.f, 0.f, 0.f, 0.f};

  for (int k0 = 0; k0 < K; k0 += 32) {
    __syncthreads();   // WAR: previous iteration's fragment reads complete
    for (int i = tid; i < BM * 4; i += 256) {
      int row = i >> 2, kc = (i & 3) << 3;
      *reinterpret_cast<short8v*>(&sAh[row * RS + kc]) =
          *reinterpret_cast<const short8v*>(&Ah[(size_t)(bm + row) * K + k0 + kc]);
      *reinterpret_cast<short8v*>(&sAl[row * RS + kc]) =
          *reinterpret_cast<const short8v*>(&Al[(size_t)(bm + row) * K + k0 + kc]);
    }
    for (int i = tid; i < BN * 4; i += 256) {
      int row = i >> 2, kc = (i & 3) << 3;
      *reinterpret_cast<short8v*>(&sBh[row * RS + kc]) =
          *reinterpret_cast<const short8v*>(&Wh[(size_t)(bn + row) * K + k0 + kc]);
      *reinterpret_cast<short8v*>(&sBl[row * RS + kc]) =
          *reinterpret_cast<const short8v*>(&Wl[(size_t)(bn + row) * K + k0 + kc]);
    }
    __syncthreads();

    short8v ah[MR], al[MR], bh[NR], bl[NR];
    #pragma unroll
    for (int m = 0; m < MR; ++m) {
      int off = (wm + m * 16 + r16) * RS + kb8;
      ah[m] = *reinterpret_cast<const short8v*>(&sAh[off]);
      al[m] = *reinterpret_cast<const short8v*>(&sAl[off]);
    }
    #pragma unroll
    for (int n = 0; n < NR; ++n) {
      int off = (wn + n * 16 + r16) * RS + kb8;
      bh[n] = *reinterpret_cast<const short8v*>(&sBh[off]);
      bl[n] = *reinterpret_cast<const short8v*>(&sBl[off]);
    }
    #pragma unroll
    for (int m = 0; m < MR; ++m)
      #pragma unroll
      for (int n = 0; n < NR; ++n)
        acc[m][n] = __builtin_amdgcn_mfma_f32_16x16x32_bf16(ah[m], bh[n], acc[m][n], 0, 0, 0);
    #pragma unroll
    for (int m = 0; m < MR; ++m)
      #pragma unroll
      for (int n = 0; n < NR; ++n)
        acc[m][n] = __builtin_amdgcn_mfma_f32_16x16x32_bf16(ah[m], bl[n], acc[m][n], 0, 0, 0);
    #pragma unroll
    for (int m = 0; m < MR; ++m)
      #pragma unroll
      for (int n = 0; n < NR; ++n)
        acc[m][n] = __builtin_amdgcn_mfma_f32_16x16x32_bf16(al[m], bh[n], acc[m][n], 0, 0, 0);
  }

  const int cr = (lane >> 4) * 4;
  #pragma unroll
  for (int m = 0; m < MR; ++m)
    #pragma unroll
    for (int n = 0; n < NR; ++n) {
      int row = bm + wm + m * 16 + cr;
      int col = bn + wn + n * 16 + r16;
      #pragma unroll
      for (int r = 0; r < 4; ++r)
        C[(size_t)(row + r) * N + col] = acc[m][n][r];
    }
}

// ---------------------------------------------------------------------------
// Depthwise 3x3 conv (SAME) + bias + SiLU, vectorized x4 over d.
// Emits f32 (for the scan) and bf16 hi/lo (for the x_dbl GEMM).
// ---------------------------------------------------------------------------
__global__ __launch_bounds__(256) void conv_silu(const float* __restrict__ xz,
                                                 const float* __restrict__ conv_wt,
                                                 const float* __restrict__ conv_b,
                                                 float* __restrict__ x_seq,
                                                 ushort* __restrict__ xsh,
                                                 ushort* __restrict__ xsl) {
  int t = blockIdx.x * 256 + threadIdx.x;      // over ML*DI/4
  int d4 = (t % (DI / 4)) * 4;
  int l  = (t / (DI / 4)) % LL;
  int b  = t / ((DI / 4) * LL);
  int h = l >> 6, w = l & 63;
  float4 acc = *reinterpret_cast<const float4*>(&conv_b[d4]);
  #pragma unroll
  for (int kh = 0; kh < 3; ++kh) {
    int hh = h + kh - 1;
    if (hh < 0 || hh >= HH) continue;
    #pragma unroll
    for (int kw = 0; kw < 3; ++kw) {
      int ww2 = w + kw - 1;
      if (ww2 < 0 || ww2 >= WW) continue;
      float4 v = *reinterpret_cast<const float4*>(
          &xz[((size_t)(b * LL + hh * WW + ww2)) * 768 + d4]);
      float4 wv = *reinterpret_cast<const float4*>(&conv_wt[(kh * 3 + kw) * DI + d4]);
      acc.x = fmaf(v.x, wv.x, acc.x); acc.y = fmaf(v.y, wv.y, acc.y);
      acc.z = fmaf(v.z, wv.z, acc.z); acc.w = fmaf(v.w, wv.w, acc.w);
    }
  }
  float4 sv;
  sv.x = acc.x / (1.f + __expf(-acc.x));
  sv.y = acc.y / (1.f + __expf(-acc.y));
  sv.z = acc.z / (1.f + __expf(-acc.z));
  sv.w = acc.w / (1.f + __expf(-acc.w));
  size_t o = (size_t)t * 4;
  *reinterpret_cast<float4*>(&x_seq[o]) = sv;
  ushort4 hh4, ll4;
  split2(sv.x, hh4.x, ll4.x); split2(sv.y, hh4.y, ll4.y);
  split2(sv.z, hh4.z, ll4.z); split2(sv.w, hh4.w, ll4.w);
  *reinterpret_cast<ushort4*>(&xsh[o]) = hh4;
  *reinterpret_cast<ushort4*>(&xsl[o]) = ll4;
}

// ---------------------------------------------------------------------------
// mid_scan: fused finish + scan pass 1 per (b, chunk) = 16-row tile.
// Native exp/log; P computed as exp(a_n * sum(delta)); delta NOT written to
// global (pass2 recomputes it cheaply). B/C still go to global for pass2.
// ---------------------------------------------------------------------------
__global__ __launch_bounds__(DI) void mid_scan(
    const float* __restrict__ xdbl,          // ML x 64
    const float* __restrict__ prompt,        // ML x DM
    const float* __restrict__ xseq,          // ML x DI
    const float* __restrict__ dt_proj_w,     // DI x RK (row-contiguous per d)
    const float* __restrict__ dt_proj_b,     // DI
    const float* __restrict__ prompt_proj_w, // NS x DM
    const float* __restrict__ A_log,         // DI x NS
    float* __restrict__ Bv, float* __restrict__ Cv,
    float* __restrict__ Pb, float* __restrict__ Qb) {
  const int d = threadIdx.x;                 // 0..383
  const int c = blockIdx.x & (NC - 1);
  const int b = blockIdx.x >> 8;
  __shared__ __align__(16) float xd[CL][48]; // x_dbl tile (44 used)
  __shared__ __align__(16) float pr[CL][DM + 4];
  __shared__ __align__(16) float pw[NS][DM + 4];
  __shared__ __align__(16) float sB[CL][NS];
  const size_t row0 = (size_t)(b * LL + c * CL);

  for (int i = d; i < CL * 12; i += DI) {    // xd: 192 float4
    int r = i / 12, c4 = (i % 12) * 4;
    *reinterpret_cast<float4*>(&xd[r][c4]) =
        *reinterpret_cast<const float4*>(&xdbl[(row0 + r) * 64 + c4]);
  }
  for (int i = d; i < CL * 48; i += DI) {    // pr: 768 float4
    int r = i / 48, c4 = (i % 48) * 4;
    *reinterpret_cast<float4*>(&pr[r][c4]) =
        *reinterpret_cast<const float4*>(&prompt[(row0 + r) * DM + c4]);
  }
  for (int i = d; i < NS * 48; i += DI) {    // pw: 768 float4
    int r = i / 48, c4 = (i % 48) * 4;
    *reinterpret_cast<float4*>(&pw[r][c4]) =
        *reinterpret_cast<const float4*>(&prompt_proj_w[r * DM + c4]);
  }

  // register-resident per-thread params
  float sdtv[RK];                            // dt_proj_w row d (contiguous)
  #pragma unroll
  for (int j = 0; j < RK; j += 4) {
    float4 v = *reinterpret_cast<const float4*>(&dt_proj_w[(size_t)d * RK + j]);
    sdtv[j] = v.x; sdtv[j+1] = v.y; sdtv[j+2] = v.z; sdtv[j+3] = v.w;
  }
  const float db2 = 2.0f * dt_proj_b[d];     // bias applied twice (faithful)
  float an[NS];                              // A (natural base, negative)
  #pragma unroll
  for (int n = 0; n < NS; n += 4) {
    float4 av = *reinterpret_cast<const float4*>(&A_log[d * NS + n]);
    an[n+0] = -__expf(av.x); an[n+1] = -__expf(av.y);
    an[n+2] = -__expf(av.z); an[n+3] = -__expf(av.w);
  }
  const size_t rowbase = row0 * DI + d;
  float xu[CL];
  #pragma unroll
  for (int s = 0; s < CL; ++s) xu[s] = xseq[rowbase + (size_t)s * DI];
  __syncthreads();                           // xd/pr/pw staged

  // delta in registers only (fast softplus)
  float dlt[CL];
  float sum_de = 0.f;
  #pragma unroll
  for (int r = 0; r < CL; ++r) {
    float acc = db2;
    #pragma unroll
    for (int j = 0; j < RK; ++j) acc = fmaf(xd[r][j], sdtv[j], acc);
    dlt[r] = softplus_fast(acc);
    sum_de += dlt[r];
  }

  // B and C (256 threads; lanes n-fast for coalesced writes)
  if (d < 256) {
    int r = d >> 4, n = d & 15;
    float bval = xd[r][12 + n];
    Bv[(row0 + r) * NS + n] = bval;
    sB[r][n] = bval;
    float acc = xd[r][28 + n];
    for (int c4 = 0; c4 < DM; c4 += 4) {
      float4 pv = *reinterpret_cast<const float4*>(&pr[r][c4]);
      float4 wv = *reinterpret_cast<const float4*>(&pw[n][c4]);
      acc = fmaf(pv.x, wv.x, acc); acc = fmaf(pv.y, wv.y, acc);
      acc = fmaf(pv.z, wv.z, acc); acc = fmaf(pv.w, wv.w, acc);
    }
    Cv[(row0 + r) * NS + n] = acc;
  }
  __syncthreads();                           // sB ready

  // pass-1 recurrence; native exp; vectorized sB reads
  float h[NS];
  #pragma unroll
  for (int n = 0; n < NS; ++n) h[n] = 0.f;
  #pragma unroll
  for (int s = 0; s < CL; ++s) {
    float de = dlt[s];
    float du = de * xu[s];
    float4 b0 = *reinterpret_cast<const float4*>(&sB[s][0]);
    float4 b1 = *reinterpret_cast<const float4*>(&sB[s][4]);
    float4 b2 = *reinterpret_cast<const float4*>(&sB[s][8]);
    float4 b3 = *reinterpret_cast<const float4*>(&sB[s][12]);
    float bb[NS] = {b0.x,b0.y,b0.z,b0.w, b1.x,b1.y,b1.z,b1.w,
                    b2.x,b2.y,b2.z,b2.w, b3.x,b3.y,b3.z,b3.w};
    #pragma unroll
    for (int n = 0; n < NS; ++n) {
      float e = __expf(de * an[n]);
      h[n] = fmaf(e, h[n], du * bb[n]);
    }
  }
  const size_t base = ((size_t)(b * NC + c) * DI + d) * NS;
  #pragma unroll
  for (int n = 0; n < NS; n += 4) {
    float4 pv = make_float4(__expf(sum_de * an[n]),   __expf(sum_de * an[n+1]),
                            __expf(sum_de * an[n+2]), __expf(sum_de * an[n+3]));
    *reinterpret_cast<float4*>(&Pb[base + n]) = pv;
    *reinterpret_cast<float4*>(&Qb[base + n]) = make_float4(h[n], h[n+1], h[n+2], h[n+3]);
  }
}

// ---------------------------------------------------------------------------
// Segmented combine: block = 16 recurrences x 16 segments (16 chunks each).
// ---------------------------------------------------------------------------
__global__ __launch_bounds__(256) void scan_combine(const float* __restrict__ Pb,
                                                    const float* __restrict__ Qb,
                                                    float* __restrict__ Hout) {
  const int tid = threadIdx.x;
  const int dnl = tid & 15;                 // local recurrence
  const int seg = tid >> 4;                 // 0..15
  const int rec = blockIdx.x * 16 + dnl;    // 0..12287
  const int b = rec / (DI * NS);
  const int dn = rec % (DI * NS);
  const size_t S = DI * NS;
  const size_t base = (size_t)b * NC * S + dn;

  float p[16], q[16];
  #pragma unroll
  for (int i = 0; i < 16; ++i) {
    p[i] = Pb[base + (size_t)(seg * 16 + i) * S];
    q[i] = Qb[base + (size_t)(seg * 16 + i) * S];
  }
  float Pa = 1.f, Qa = 0.f;
  #pragma unroll
  for (int i = 0; i < 16; ++i) { Qa = fmaf(p[i], Qa, q[i]); Pa *= p[i]; }

  __shared__ float sP[16][17], sQ[16][17], sH[16][17];
  sP[dnl][seg] = Pa; sQ[dnl][seg] = Qa;
  __syncthreads();
  if (tid < 16) {                           // serial scan over 16 segments
    float hh = 0.f;
    #pragma unroll
    for (int s2 = 0; s2 < 16; ++s2) {
      sH[tid][s2] = hh;
      hh = fmaf(sP[tid][s2], hh, sQ[tid][s2]);
    }
  }
  __syncthreads();
  float h = sH[dnl][seg];
  #pragma unroll
  for (int i = 0; i < 16; ++i) {
    Hout[base + (size_t)(seg * 16 + i) * S] = h;
    h = fmaf(p[i], h, q[i]);
  }
}

// ---------------------------------------------------------------------------
// Pass 2 + fused LN + SiLU gate. Recomputes delta from xdbl[:12] (cheap; saves
// the 25 MB delta round-trip). Native exp/log throughout.
// ---------------------------------------------------------------------------
__global__ __launch_bounds__(DI) void scan_pass2_ln(
    const float* __restrict__ xdbl, const float* __restrict__ x_seq,
    const float* __restrict__ Bv, const float* __restrict__ Cv,
    const float* __restrict__ dt_proj_w, const float* __restrict__ dt_proj_b,
    const float* __restrict__ A_log, const float* __restrict__ Dp,
    const float* __restrict__ hin, const float* __restrict__ xz,
    const float* __restrict__ ln_g, const float* __restrict__ ln_b,
    ushort* __restrict__ ygh, ushort* __restrict__ ygl) {
  const int d = threadIdx.x;
  const int c = blockIdx.x & (NC - 1);
  const int b = blockIdx.x >> 8;
  __shared__ __align__(16) float xd[CL][12];
  __shared__ float sB[CL][NS], sC[CL][NS];
  __shared__ float sY[CL][DI + 1];
  const size_t row0 = (size_t)(b * LL + c * CL);
  for (int idx = threadIdx.x; idx < CL * NS; idx += DI) {
    size_t g = (size_t)(b * LL + c * CL) * NS + idx;
    sB[idx >> 4][idx & 15] = Bv[g];
    sC[idx >> 4][idx & 15] = Cv[g];
  }
  for (int i = d; i < CL * 3; i += DI) {     // 48 float4: xdbl[:, 0..11]
    int r = i / 3, c4 = (i % 3) * 4;
    *reinterpret_cast<float4*>(&xd[r][c4]) =
        *reinterpret_cast<const float4*>(&xdbl[(row0 + r) * 64 + c4]);
  }
  const size_t rowbase = row0 * DI + d;
  float xu[CL];
  #pragma unroll
  for (int s = 0; s < CL; ++s) xu[s] = x_seq[rowbase + (size_t)s * DI];

  float sdtv[RK];
  #pragma unroll
  for (int j = 0; j < RK; j += 4) {
    float4 v = *reinterpret_cast<const float4*>(&dt_proj_w[(size_t)d * RK + j]);
    sdtv[j] = v.x; sdtv[j+1] = v.y; sdtv[j+2] = v.z; sdtv[j+3] = v.w;
  }
  const float db2 = 2.0f * dt_proj_b[d];
  float an[NS], h[NS];
  const size_t hbase = ((size_t)(b * NC + c) * DI + d) * NS;
  #pragma unroll
  for (int n = 0; n < NS; n += 4) {
    float4 hv = *reinterpret_cast<const float4*>(&hin[hbase + n]);
    h[n] = hv.x; h[n+1] = hv.y; h[n+2] = hv.z; h[n+3] = hv.w;
  }
  #pragma unroll
  for (int n = 0; n < NS; n += 4) {
    float4 av = *reinterpret_cast<const float4*>(&A_log[d * NS + n]);
    an[n+0] = -__expf(av.x); an[n+1] = -__expf(av.y);
    an[n+2] = -__expf(av.z); an[n+3] = -__expf(av.w);
  }
  const float Dd = Dp[d];
  __syncthreads();                           // xd/sB/sC staged

  // phase 1: recurrence, no barriers (delta recomputed in regs)
  #pragma unroll
  for (int s = 0; s < CL; ++s) {
    float dacc = db2;
    #pragma unroll
    for (int j = 0; j < RK; ++j) dacc = fmaf(xd[s][j], sdtv[j], dacc);
    float de = softplus_fast(dacc);
    float u  = xu[s];
    float du = de * u;
    float acc = Dd * u;
    float4 b0 = *reinterpret_cast<const float4*>(&sB[s][0]);
    float4 b1 = *reinterpret_cast<const float4*>(&sB[s][4]);
    float4 b2 = *reinterpret_cast<const float4*>(&sB[s][8]);
    float4 b3 = *reinterpret_cast<const float4*>(&sB[s][12]);
    float bb[NS] = {b0.x,b0.y,b0.z,b0.w, b1.x,b1.y,b1.z,b1.w,
                    b2.x,b2.y,b2.z,b2.w, b3.x,b3.y,b3.z,b3.w};
    float4 c0 = *reinterpret_cast<const float4*>(&sC[s][0]);
    float4 c1 = *reinterpret_cast<const float4*>(&sC[s][4]);
    float4 c2 = *reinterpret_cast<const float4*>(&sC[s][8]);
    float4 c3 = *reinterpret_cast<const float4*>(&sC[s][12]);
    float cc[NS] = {c0.x,c0.y,c0.z,c0.w, c1.x,c1.y,c1.z,c1.w,
                    c2.x,c2.y,c2.z,c2.w, c3.x,c3.y,c3.z,c3.w};
    #pragma unroll
    for (int n = 0; n < NS; ++n) {
      float e = __expf(de * an[n]);
      h[n] = fmaf(e, h[n], du * bb[n]);
      acc = fmaf(h[n], cc[n], acc);
    }
    sY[s][d] = acc;
  }
  __syncthreads();

  // phase 2: wave-per-row LayerNorm + gate + bf16 split
  const int wv = d >> 6, lane = d & 63;
  float lg[6], lb[6];
  #pragma unroll
  for (int k = 0; k < 6; ++k) { lg[k] = ln_g[lane + k * 64]; lb[k] = ln_b[lane + k * 64]; }
  for (int r = wv; r < CL; r += 6) {
    const size_t row = row0 + r;
    float v[6];
    float sum = 0.f, sq = 0.f;
    #pragma unroll
    for (int k = 0; k < 6; ++k) {
      v[k] = sY[r][lane + k * 64];
      sum += v[k];
      sq = fmaf(v[k], v[k], sq);
    }
    #pragma unroll
    for (int off = 32; off >= 1; off >>= 1) {
      sum += __shfl_xor(sum, off, 64);
      sq  += __shfl_xor(sq,  off, 64);
    }
    const float mu = sum * (1.f / DI);
    const float var = sq * (1.f / DI) - mu * mu;
    const float rstd = rsqrtf(var + 1e-5f);
    #pragma unroll
    for (int k = 0; k < 6; ++k) {
      int dd = lane + k * 64;
      float t = (v[k] - mu) * rstd * lg[k] + lb[k];
      float z = xz[row * 768 + DI + dd];
      float outv = t * (z / (1.f + __expf(-z)));
      ushort hh16, ll16;
      split2(outv, hh16, ll16);
      ygh[row * DI + dd] = hh16;
      ygl[row * DI + dd] = ll16;
    }
  }
}

// ---------------------------------------------------------------------------
extern "C" void kernel_launch(void* const* d_in, const int* in_sizes, int n_in,
                              void* d_out, int out_size, void* d_ws, size_t ws_size,
                              hipStream_t stream) {
  const float* x             = (const float*)d_in[0];
  const float* prompt        = (const float*)d_in[1];
  const float* in_proj_w     = (const float*)d_in[2];
  const float* conv_w        = (const float*)d_in[3];
  const float* conv_b        = (const float*)d_in[4];
  const float* x_proj_w      = (const float*)d_in[5];
  const float* dt_proj_w     = (const float*)d_in[6];
  const float* dt_proj_b     = (const float*)d_in[7];
  const float* A_log         = (const float*)d_in[8];
  const float* Dp            = (const float*)d_in[9];
  const float* prompt_proj_w = (const float*)d_in[10];
  const float* ln_g          = (const float*)d_in[11];
  const float* ln_b          = (const float*)d_in[12];
  const float* out_proj_w    = (const float*)d_in[13];
  float* out = (float*)d_out;

  // workspace layout (bytes), ~124 MB (ws is 256 MiB)
  char* p = (char*)d_ws;
  auto alloc = [&](size_t bytes) { char* r = p; p += (bytes + 255) & ~(size_t)255; return r; };
  float*  xz    = (float*)alloc((size_t)ML * 768 * 4);
  float*  xseq  = (float*)alloc((size_t)ML * DI * 4);
  float*  xdbl  = (float*)alloc((size_t)ML * 64 * 4);
  float*  bv    = (float*)alloc((size_t)ML * NS * 4);
  float*  cv    = (float*)alloc((size_t)ML * NS * 4);
  float*  pb    = (float*)alloc((size_t)BB * NC * DI * NS * 4);
  float*  qb    = (float*)alloc((size_t)BB * NC * DI * NS * 4);
  float*  hin   = (float*)alloc((size_t)BB * NC * DI * NS * 4);
  ushort* w1h   = (ushort*)alloc((size_t)768 * DM * 2);
  ushort* w1l   = (ushort*)alloc((size_t)768 * DM * 2);
  ushort* w2h   = (ushort*)alloc((size_t)DM * DI * 2);
  ushort* w2l   = (ushort*)alloc((size_t)DM * DI * 2);
  ushort* wxh   = (ushort*)alloc((size_t)64 * DI * 2);
  ushort* wxl   = (ushort*)alloc((size_t)64 * DI * 2);
  ushort* xh    = (ushort*)alloc((size_t)ML * DM * 2);
  ushort* xl    = (ushort*)alloc((size_t)ML * DM * 2);
  ushort* xsh   = (ushort*)alloc((size_t)ML * DI * 2);
  ushort* xsl   = (ushort*)alloc((size_t)ML * DI * 2);
  ushort* ygh   = (ushort*)alloc((size_t)ML * DI * 2);
  ushort* ygl   = (ushort*)alloc((size_t)ML * DI * 2);
  float*  cwt   = (float*)alloc((size_t)9 * DI * 4);

  prep<<<1790, 256, 0, stream>>>(in_proj_w, out_proj_w, x_proj_w, x, conv_w,
                                 w1h, w1l, w2h, w2l, wxh, wxl, xh, xl, cwt);
  // in_proj: xz = x @ in_proj_w^T (8192 x 768, K=192); 1024 blocks = 4/CU
  gemm_sp<64, 96, 2, 3><<<dim3(8, 128), 256, 0, stream>>>(xh, xl, w1h, w1l, xz, ML, 768, DM);
  conv_silu<<<(ML * DI / 4) / 256, 256, 0, stream>>>(xz, cwt, conv_b, xseq, xsh, xsl);
  // x_dbl = x_seq @ x_proj_w^T (padded to 64 cols, K=384); 256 blocks
  gemm_sp<32, 64, 1, 2><<<dim3(1, 256), 256, 0, stream>>>(xsh, xsl, wxh, wxl, xdbl, ML, 64, DI);
  mid_scan<<<BB * NC, DI, 0, stream>>>(xdbl, prompt, xseq, dt_proj_w, dt_proj_b,
                                       prompt_proj_w, A_log, bv, cv, pb, qb);
  scan_combine<<<(BB * DI * NS) / 16, 256, 0, stream>>>(pb, qb, hin);
  scan_pass2_ln<<<BB * NC, DI, 0, stream>>>(xdbl, xseq, bv, cv, dt_proj_w, dt_proj_b,
                                            A_log, Dp, hin, xz, ln_g, ln_b, ygh, ygl);
  // out = yg @ out_proj_w^T (8192 x 192, K=384); 768 blocks = 3/CU
  gemm_sp<32, 64, 1, 2><<<dim3(3, 256), 256, 0, stream>>>(ygh, ygl, w2h, w2l, out, ML, DM, DI);
}